// Round 1
// baseline (3797.506 us; speedup 1.0000x reference)
//
#include <hip/hip_runtime.h>
#include <math.h>

// Problem constants (DecoderLayer, fp32)
constexpr int Bsz = 4, T = 2048, C = 1024, H = 16, HD = 64, F = 4096;
constexpr int M = Bsz * T; // 8192 rows

// ---------------------------------------------------------------------------
// LayerNorm: one block per row (1024 floats), 256 threads * float4
// ---------------------------------------------------------------------------
__global__ __launch_bounds__(256) void ln_kernel(const float* __restrict__ x,
                                                 const float* __restrict__ g,
                                                 const float* __restrict__ b,
                                                 float* __restrict__ out) {
  const int row = blockIdx.x;
  const int tid = threadIdx.x;
  const float4 v = ((const float4*)(x + (size_t)row * C))[tid];
  float s = v.x + v.y + v.z + v.w;
  float ss = v.x * v.x + v.y * v.y + v.z * v.z + v.w * v.w;
#pragma unroll
  for (int off = 32; off > 0; off >>= 1) {
    s += __shfl_xor(s, off, 64);
    ss += __shfl_xor(ss, off, 64);
  }
  __shared__ float red[2][4];
  const int wv = tid >> 6;
  if ((tid & 63) == 0) { red[0][wv] = s; red[1][wv] = ss; }
  __syncthreads();
  s = red[0][0] + red[0][1] + red[0][2] + red[0][3];
  ss = red[1][0] + red[1][1] + red[1][2] + red[1][3];
  const float mu = s * (1.0f / C);
  const float var = ss * (1.0f / C) - mu * mu;
  const float rstd = rsqrtf(var + 1e-5f);
  const float4 gv = ((const float4*)g)[tid];
  const float4 bv = ((const float4*)b)[tid];
  float4 o;
  o.x = (v.x - mu) * rstd * gv.x + bv.x;
  o.y = (v.y - mu) * rstd * gv.y + bv.y;
  o.z = (v.z - mu) * rstd * gv.z + bv.z;
  o.w = (v.w - mu) * rstd * gv.w + bv.w;
  ((float4*)(out + (size_t)row * C))[tid] = o;
}

// ---------------------------------------------------------------------------
// QKV projection: norm[8192,1024] @ W{q,k,v}[h][1024,64] -> {Q,K,V}[B,H,T,HD]
// grid: (M/64, 48); z = blockIdx.y: wsel = z>>4, h = z&15
// ---------------------------------------------------------------------------
__global__ __launch_bounds__(256) void qkv_kernel(const float* __restrict__ A,
                                                  const float* __restrict__ Wq,
                                                  const float* __restrict__ Wk,
                                                  const float* __restrict__ Wv,
                                                  float* __restrict__ Qo,
                                                  float* __restrict__ Ko,
                                                  float* __restrict__ Vo) {
  __shared__ float As[16][68];  // [k][m], transposed stage
  __shared__ float Bs[16][68];  // [k][n]
  const int tid = threadIdx.x;
  const int tx = tid & 15, ty = tid >> 4;
  const int m0 = blockIdx.x * 64;
  const int z = blockIdx.y;
  const int wsel = z >> 4, h = z & 15;
  const float* W = (wsel == 0 ? Wq : (wsel == 1 ? Wk : Wv)) + (size_t)h * C * HD;
  float* O = (wsel == 0 ? Qo : (wsel == 1 ? Ko : Vo));
  const int a_r = tid >> 2, a_c = (tid & 3) * 4;
  const int b_r = tid >> 4, b_c = (tid & 15) * 4;
  float acc[4][4] = {};
  for (int k0 = 0; k0 < C; k0 += 16) {
    const float4 av = *(const float4*)&A[(size_t)(m0 + a_r) * C + k0 + a_c];
    const float4 bv = *(const float4*)&W[(size_t)(k0 + b_r) * HD + b_c];
    __syncthreads();
    As[a_c + 0][a_r] = av.x; As[a_c + 1][a_r] = av.y;
    As[a_c + 2][a_r] = av.z; As[a_c + 3][a_r] = av.w;
    *(float4*)&Bs[b_r][b_c] = bv;
    __syncthreads();
#pragma unroll
    for (int kk = 0; kk < 16; ++kk) {
      const float4 a4 = *(const float4*)&As[kk][ty * 4];
      const float4 b4 = *(const float4*)&Bs[kk][tx * 4];
      const float a_[4] = {a4.x, a4.y, a4.z, a4.w};
      const float b_[4] = {b4.x, b4.y, b4.z, b4.w};
#pragma unroll
      for (int i = 0; i < 4; ++i)
#pragma unroll
        for (int j = 0; j < 4; ++j) acc[i][j] = fmaf(a_[i], b_[j], acc[i][j]);
    }
  }
#pragma unroll
  for (int i = 0; i < 4; ++i) {
    const int m = m0 + ty * 4 + i;
    const int bb = m >> 11, t = m & (T - 1);
    float4 o = {acc[i][0], acc[i][1], acc[i][2], acc[i][3]};
    *(float4*)(O + (((size_t)bb * H + h) * T + t) * HD + tx * 4) = o;
  }
}

// ---------------------------------------------------------------------------
// Flash attention (fp32, causal): grid (T/64, B*H), 256 threads
// LDS: Qs[d][r], KP (K as [d][s], reused as P^T [s][r]), Vs[s][d]
// ---------------------------------------------------------------------------
__global__ __launch_bounds__(256) void attn_kernel(const float* __restrict__ Q,
                                                   const float* __restrict__ K,
                                                   const float* __restrict__ V,
                                                   float* __restrict__ O) {
  __shared__ float Qs[64][68];
  __shared__ float KP[64][68];
  __shared__ float Vs[64][68];
  const int tid = threadIdx.x;
  const int tx = tid & 15, ty = tid >> 4;
  const int qt = blockIdx.x, bh = blockIdx.y;
  const float* Qg = Q + ((size_t)bh * T + (size_t)qt * 64) * HD;
  const float* Kg = K + (size_t)bh * T * HD;
  const float* Vg = V + (size_t)bh * T * HD;

#pragma unroll
  for (int c = 0; c < 4; ++c) {
    const int idx = c * 1024 + tid * 4;
    const int r = idx >> 6, d = idx & 63;
    const float4 v = *(const float4*)&Qg[idx];
    Qs[d + 0][r] = v.x; Qs[d + 1][r] = v.y; Qs[d + 2][r] = v.z; Qs[d + 3][r] = v.w;
  }
  float m_i[4], l_i[4], acc[4][4];
#pragma unroll
  for (int i = 0; i < 4; ++i) {
    m_i[i] = -INFINITY; l_i[i] = 0.0f;
#pragma unroll
    for (int j = 0; j < 4; ++j) acc[i][j] = 0.0f;
  }
  __syncthreads();

  for (int kt = 0; kt <= qt; ++kt) {
    // stage K (transposed) and V (natural)
#pragma unroll
    for (int c = 0; c < 4; ++c) {
      const int idx = c * 1024 + tid * 4;
      const int r = idx >> 6, d = idx & 63;
      const float4 kv = *(const float4*)&Kg[(size_t)kt * 64 * HD + idx];
      const float4 vv = *(const float4*)&Vg[(size_t)kt * 64 * HD + idx];
      KP[d + 0][r] = kv.x; KP[d + 1][r] = kv.y; KP[d + 2][r] = kv.z; KP[d + 3][r] = kv.w;
      *(float4*)&Vs[r][d] = vv;
    }
    __syncthreads();

    float s_acc[4][4] = {};
#pragma unroll 16
    for (int d = 0; d < 64; ++d) {
      const float4 a4 = *(const float4*)&Qs[d][ty * 4];
      const float4 b4 = *(const float4*)&KP[d][tx * 4];
      const float a_[4] = {a4.x, a4.y, a4.z, a4.w};
      const float b_[4] = {b4.x, b4.y, b4.z, b4.w};
#pragma unroll
      for (int i = 0; i < 4; ++i)
#pragma unroll
        for (int j = 0; j < 4; ++j) s_acc[i][j] = fmaf(a_[i], b_[j], s_acc[i][j]);
    }
#pragma unroll
    for (int i = 0; i < 4; ++i)
#pragma unroll
      for (int j = 0; j < 4; ++j) s_acc[i][j] *= 0.125f;
    if (kt == qt) {
#pragma unroll
      for (int i = 0; i < 4; ++i)
#pragma unroll
        for (int j = 0; j < 4; ++j)
          if (tx * 4 + j > ty * 4 + i) s_acc[i][j] = -INFINITY;
    }
    // online softmax: row stats across the 16 tx lanes
    float p[4][4], rmax[4], rsum[4];
#pragma unroll
    for (int i = 0; i < 4; ++i) {
      rmax[i] = fmaxf(fmaxf(s_acc[i][0], s_acc[i][1]), fmaxf(s_acc[i][2], s_acc[i][3]));
#pragma unroll
      for (int off = 1; off < 16; off <<= 1)
        rmax[i] = fmaxf(rmax[i], __shfl_xor(rmax[i], off, 16));
      const float m_new = fmaxf(m_i[i], rmax[i]);
      const float alpha = __expf(m_i[i] - m_new);
#pragma unroll
      for (int j = 0; j < 4; ++j) p[i][j] = __expf(s_acc[i][j] - m_new);
      rsum[i] = p[i][0] + p[i][1] + p[i][2] + p[i][3];
#pragma unroll
      for (int off = 1; off < 16; off <<= 1) rsum[i] += __shfl_xor(rsum[i], off, 16);
      l_i[i] = l_i[i] * alpha + rsum[i];
      m_i[i] = m_new;
#pragma unroll
      for (int j = 0; j < 4; ++j) acc[i][j] *= alpha;
    }
    __syncthreads();  // everyone done reading KP as K
#pragma unroll
    for (int i = 0; i < 4; ++i)
#pragma unroll
      for (int j = 0; j < 4; ++j) KP[tx * 4 + j][ty * 4 + i] = p[i][j];
    __syncthreads();  // P^T ready
#pragma unroll 16
    for (int s = 0; s < 64; ++s) {
      const float4 a4 = *(const float4*)&KP[s][ty * 4];
      const float4 b4 = *(const float4*)&Vs[s][tx * 4];
      const float a_[4] = {a4.x, a4.y, a4.z, a4.w};
      const float b_[4] = {b4.x, b4.y, b4.z, b4.w};
#pragma unroll
      for (int i = 0; i < 4; ++i)
#pragma unroll
        for (int j = 0; j < 4; ++j) acc[i][j] = fmaf(a_[i], b_[j], acc[i][j]);
    }
    __syncthreads();  // safe to restage next K/V
  }
  const int bb = bh >> 4, h = bh & 15;
#pragma unroll
  for (int i = 0; i < 4; ++i) {
    const float inv = 1.0f / l_i[i];
    const int trow = qt * 64 + ty * 4 + i;
    float4 o = {acc[i][0] * inv, acc[i][1] * inv, acc[i][2] * inv, acc[i][3] * inv};
    *(float4*)(O + ((size_t)bb * T + trow) * C + h * HD + tx * 4) = o;
  }
}

// ---------------------------------------------------------------------------
// Generic GEMM + epilogue: C = A[M,K] @ B[K,N] + bias (+residual) (+GELU)
// grid (N/64, M/64), 256 threads, 4x4 per thread
// ---------------------------------------------------------------------------
template <bool GELU, bool RES>
__global__ __launch_bounds__(256) void gemm_kernel(const float* __restrict__ A,
                                                   const float* __restrict__ Bm,
                                                   const float* __restrict__ bias,
                                                   const float* __restrict__ resid,
                                                   float* __restrict__ Cout,
                                                   int Mn, int N, int K) {
  __shared__ float As[16][68];
  __shared__ float Bs[16][68];
  const int tid = threadIdx.x;
  const int tx = tid & 15, ty = tid >> 4;
  const int m0 = blockIdx.y * 64, n0 = blockIdx.x * 64;
  const int a_r = tid >> 2, a_c = (tid & 3) * 4;
  const int b_r = tid >> 4, b_c = (tid & 15) * 4;
  float acc[4][4] = {};
  for (int k0 = 0; k0 < K; k0 += 16) {
    const float4 av = *(const float4*)&A[(size_t)(m0 + a_r) * K + k0 + a_c];
    const float4 bv = *(const float4*)&Bm[(size_t)(k0 + b_r) * N + n0 + b_c];
    __syncthreads();
    As[a_c + 0][a_r] = av.x; As[a_c + 1][a_r] = av.y;
    As[a_c + 2][a_r] = av.z; As[a_c + 3][a_r] = av.w;
    *(float4*)&Bs[b_r][b_c] = bv;
    __syncthreads();
#pragma unroll
    for (int kk = 0; kk < 16; ++kk) {
      const float4 a4 = *(const float4*)&As[kk][ty * 4];
      const float4 b4 = *(const float4*)&Bs[kk][tx * 4];
      const float a_[4] = {a4.x, a4.y, a4.z, a4.w};
      const float b_[4] = {b4.x, b4.y, b4.z, b4.w};
#pragma unroll
      for (int i = 0; i < 4; ++i)
#pragma unroll
        for (int j = 0; j < 4; ++j) acc[i][j] = fmaf(a_[i], b_[j], acc[i][j]);
    }
  }
#pragma unroll
  for (int i = 0; i < 4; ++i) {
    const size_t row = m0 + ty * 4 + i;
#pragma unroll
    for (int j = 0; j < 4; ++j) {
      const int col = n0 + tx * 4 + j;
      float v = acc[i][j] + bias[col];
      if (GELU) v = 0.5f * v * (1.0f + erff(v * 0.70710678118654752f));
      if (RES) v += resid[row * N + col];
      Cout[row * N + col] = v;
    }
  }
}

// ---------------------------------------------------------------------------
extern "C" void kernel_launch(void* const* d_in, const int* in_sizes, int n_in,
                              void* d_out, int out_size, void* d_ws, size_t ws_size,
                              hipStream_t stream) {
  (void)in_sizes; (void)n_in; (void)out_size; (void)ws_size;
  const float* x   = (const float*)d_in[0];
  const float* Wq  = (const float*)d_in[1];
  const float* Wk  = (const float*)d_in[2];
  const float* Wv  = (const float*)d_in[3];
  const float* Wo  = (const float*)d_in[4];
  const float* bo  = (const float*)d_in[5];
  const float* g1  = (const float*)d_in[6];
  const float* be1 = (const float*)d_in[7];
  const float* g2  = (const float*)d_in[8];
  const float* be2 = (const float*)d_in[9];
  const float* W1  = (const float*)d_in[10];
  const float* b1  = (const float*)d_in[11];
  const float* W2  = (const float*)d_in[12];
  const float* b2  = (const float*)d_in[13];
  float* out = (float*)d_out;
  float* ws = (float*)d_ws;

  const size_t SZ = (size_t)M * C;  // 8,388,608 floats = 32 MB
  float* norm  = ws;            // LN1 out; later reused for LN2 out
  float* Qb    = ws + SZ;       // [B,H,T,HD]
  float* Kb    = ws + 2 * SZ;
  float* Vb    = ws + 3 * SZ;
  float* attnC = ws + 4 * SZ;   // [B,T,C] (heads concatenated)
  float* res   = ws + 5 * SZ;   // x + attn_out
  float* hbuf  = ws + SZ;       // [M,F] = 4*SZ, aliases Qb..attnC (dead by then)
  // total ws: 6*SZ*4B = 192 MB

  ln_kernel<<<M, 256, 0, stream>>>(x, g1, be1, norm);
  qkv_kernel<<<dim3(M / 64, 48), 256, 0, stream>>>(norm, Wq, Wk, Wv, Qb, Kb, Vb);
  attn_kernel<<<dim3(T / 64, Bsz * H), 256, 0, stream>>>(Qb, Kb, Vb, attnC);
  gemm_kernel<false, true><<<dim3(C / 64, M / 64), 256, 0, stream>>>(
      attnC, Wo, bo, x, res, M, C, C);
  ln_kernel<<<M, 256, 0, stream>>>(res, g2, be2, norm);
  gemm_kernel<true, false><<<dim3(F / 64, M / 64), 256, 0, stream>>>(
      norm, W1, b1, nullptr, hbuf, M, F, C);
  gemm_kernel<false, true><<<dim3(C / 64, M / 64), 256, 0, stream>>>(
      hbuf, W2, b2, res, out, M, C, F);
}

// Round 7
// 756.151 us; speedup vs baseline: 5.0222x; 5.0222x over previous
//
#include <hip/hip_runtime.h>
#include <math.h>

// Problem constants (DecoderLayer, fp32 in/out)
constexpr int Bsz = 4, T = 2048, C = 1024, H = 16, HD = 64, F = 4096;
constexpr int M = Bsz * T;  // 8192 rows

typedef _Float16 f16x8 __attribute__((ext_vector_type(8)));
typedef float f32x4 __attribute__((ext_vector_type(4)));
typedef unsigned int u32;

__device__ __forceinline__ void async_copy16(void* lds, const void* g) {
  __builtin_amdgcn_global_load_lds((const __attribute__((address_space(1))) u32*)g,
                                   (__attribute__((address_space(3))) u32*)lds, 16, 0, 0);
}

union H4 { _Float16 h[4]; uint2 u; };

// ---------------------------------------------------------------------------
// LayerNorm: one block per row (1024 floats), 256 threads * float4, fp16 out
// ---------------------------------------------------------------------------
__global__ __launch_bounds__(256) void ln_kernel(const float* __restrict__ x,
                                                 const float* __restrict__ g,
                                                 const float* __restrict__ b,
                                                 _Float16* __restrict__ outh) {
  const int row = blockIdx.x;
  const int tid = threadIdx.x;
  const float4 v = ((const float4*)(x + (size_t)row * C))[tid];
  float s = v.x + v.y + v.z + v.w;
  float ss = v.x * v.x + v.y * v.y + v.z * v.z + v.w * v.w;
#pragma unroll
  for (int off = 32; off > 0; off >>= 1) {
    s += __shfl_xor(s, off, 64);
    ss += __shfl_xor(ss, off, 64);
  }
  __shared__ float red[2][4];
  const int wv = tid >> 6;
  if ((tid & 63) == 0) { red[0][wv] = s; red[1][wv] = ss; }
  __syncthreads();
  s = red[0][0] + red[0][1] + red[0][2] + red[0][3];
  ss = red[1][0] + red[1][1] + red[1][2] + red[1][3];
  const float mu = s * (1.0f / C);
  const float var = ss * (1.0f / C) - mu * mu;
  const float rstd = rsqrtf(var + 1e-5f);
  const float4 gv = ((const float4*)g)[tid];
  const float4 bv = ((const float4*)b)[tid];
  H4 pk;
  pk.h[0] = (_Float16)((v.x - mu) * rstd * gv.x + bv.x);
  pk.h[1] = (_Float16)((v.y - mu) * rstd * gv.y + bv.y);
  pk.h[2] = (_Float16)((v.z - mu) * rstd * gv.z + bv.z);
  pk.h[3] = (_Float16)((v.w - mu) * rstd * gv.w + bv.w);
  ((uint2*)(outh + (size_t)row * C))[tid] = pk.u;
}

// ---------------------------------------------------------------------------
// Generic transpose+convert: W[K][N] fp32 -> WT[N][K] fp16. grid (N/64, K/64)
// ---------------------------------------------------------------------------
__global__ __launch_bounds__(256) void tconv(const float* __restrict__ W,
                                             _Float16* __restrict__ WT,
                                             int K, int N) {
  __shared__ float tile[64][65];
  const int tid = threadIdx.x;
  const int n0 = blockIdx.x * 64, k0 = blockIdx.y * 64;
#pragma unroll
  for (int i = 0; i < 4; ++i) {
    const int idx = i * 1024 + tid * 4;
    const int r = idx >> 6, c = idx & 63;
    const float4 v = *(const float4*)&W[(size_t)(k0 + r) * N + n0 + c];
    tile[r][c] = v.x; tile[r][c + 1] = v.y; tile[r][c + 2] = v.z; tile[r][c + 3] = v.w;
  }
  __syncthreads();
#pragma unroll
  for (int i = 0; i < 4; ++i) {
    const int idx = i * 1024 + tid * 4;
    const int r = idx >> 6, c = idx & 63;
    H4 pk;
#pragma unroll
    for (int j = 0; j < 4; ++j) pk.h[j] = (_Float16)tile[c + j][r];
    *(uint2*)&WT[(size_t)(n0 + r) * K + k0 + c] = pk.u;
  }
}

// ---------------------------------------------------------------------------
// QKV weights: Wq/Wk/Wv [16][1024][64] fp32 -> WcatT [3072][1024] fp16
// ---------------------------------------------------------------------------
__global__ __launch_bounds__(256) void tconv_qkv(const float* __restrict__ Wq,
                                                 const float* __restrict__ Wk,
                                                 const float* __restrict__ Wv,
                                                 _Float16* __restrict__ WcatT) {
  __shared__ float tile[64][65];
  const int tid = threadIdx.x;
  const int c0 = blockIdx.x * 64;
  const int h = blockIdx.y, wsel = blockIdx.z;
  const float* W = (wsel == 0 ? Wq : (wsel == 1 ? Wk : Wv)) + (size_t)h * C * HD;
  const int base_row = wsel * 1024 + h * 64;
#pragma unroll
  for (int i = 0; i < 4; ++i) {
    const int idx = i * 1024 + tid * 4;
    const int r = idx >> 6, c = idx & 63;
    const float4 v = *(const float4*)&W[(size_t)(c0 + r) * HD + c];
    tile[r][c] = v.x; tile[r][c + 1] = v.y; tile[r][c + 2] = v.z; tile[r][c + 3] = v.w;
  }
  __syncthreads();
#pragma unroll
  for (int i = 0; i < 4; ++i) {
    const int idx = i * 1024 + tid * 4;
    const int r = idx >> 6, c = idx & 63;
    H4 pk;
#pragma unroll
    for (int j = 0; j < 4; ++j) pk.h[j] = (_Float16)tile[c + j][r];
    *(uint2*)&WcatT[(size_t)(base_row + r) * C + c0 + c] = pk.u;
  }
}

// ---------------------------------------------------------------------------
// MFMA fp16 GEMM: C = A[M,K] @ B^T  (B stored [N][K] fp16)
// 128x128 tile, BK=64, 4 waves, mfma_f32_16x16x32_f16
// MODE 0: QKV  -> Qh fp16 (scaled 1/8) [bh][t][d], Kh fp16 [bh][t][d],
//                 Vth fp16 transposed [bh][d][t]
// MODE 1: WO   -> +bias +resid, fp32 out
// MODE 2: FFN1 -> +bias, GELU, fp16 out
// MODE 3: FFN2 -> +bias +resid, fp32 out
// ---------------------------------------------------------------------------
template <int MODE>
__global__ __launch_bounds__(256) void mgemm(const _Float16* __restrict__ Ah,
                                             const _Float16* __restrict__ Bh,
                                             const float* __restrict__ bias,
                                             const float* __restrict__ resid,
                                             float* __restrict__ Of,
                                             _Float16* __restrict__ Oh,
                                             _Float16* __restrict__ Oh2,
                                             _Float16* __restrict__ Oh3,
                                             int Ndim, int Kdim) {
  __shared__ _Float16 Alds[128 * 64];
  __shared__ _Float16 Blds[128 * 64];
  const int tid = threadIdx.x;
  const int wv = tid >> 6, ln = tid & 63;
  const int wm = wv >> 1, wn = wv & 1;
  const int m0 = blockIdx.y * 128, n0 = blockIdx.x * 128;
  const int lr = ln & 15, lk = ln >> 4;

  const _Float16* Abase = Ah + (size_t)m0 * Kdim;
  const _Float16* Bbase = Bh + (size_t)n0 * Kdim;

  f32x4 acc[4][4] = {};

  for (int k0 = 0; k0 < Kdim; k0 += 64) {
    __syncthreads();
#pragma unroll
    for (int i = 0; i < 4; ++i) {
      const int seg = wv * 4 + i;
      const int row = seg * 8 + (ln >> 3);
      async_copy16(Alds + seg * 512, Abase + (size_t)row * Kdim + k0 + (ln & 7) * 8);
      async_copy16(Blds + seg * 512, Bbase + (size_t)row * Kdim + k0 + (ln & 7) * 8);
    }
    __syncthreads();
#pragma unroll
    for (int kk = 0; kk < 2; ++kk) {
      f16x8 af[4], bf[4];
#pragma unroll
      for (int fm = 0; fm < 4; ++fm)
        af[fm] = *(const f16x8*)&Alds[(wm * 64 + fm * 16 + lr) * 64 + kk * 32 + lk * 8];
#pragma unroll
      for (int fn = 0; fn < 4; ++fn)
        bf[fn] = *(const f16x8*)&Blds[(wn * 64 + fn * 16 + lr) * 64 + kk * 32 + lk * 8];
#pragma unroll
      for (int fm = 0; fm < 4; ++fm)
#pragma unroll
        for (int fn = 0; fn < 4; ++fn)
          acc[fm][fn] = __builtin_amdgcn_mfma_f32_16x16x32_f16(af[fm], bf[fn], acc[fm][fn], 0, 0, 0);
    }
  }

  // Epilogue. D layout: col = ln&15, row = (ln>>4)*4 + r
#pragma unroll
  for (int fm = 0; fm < 4; ++fm) {
#pragma unroll
    for (int fn = 0; fn < 4; ++fn) {
      const int row0 = m0 + wm * 64 + fm * 16 + lk * 4;
      const int col = n0 + wn * 64 + fn * 16 + lr;
      const f32x4 v = acc[fm][fn];
      if (MODE == 0) {
        const int wsel = col >> 10, h = (col >> 6) & 15, d = col & 63;
#pragma unroll
        for (int r = 0; r < 4; ++r) {
          const int m = row0 + r;
          const int bb = m >> 11, t = m & (T - 1);
          if (wsel == 0)
            Oh[(((size_t)bb * H + h) * T + t) * HD + d] = (_Float16)(v[r] * 0.125f);
          else if (wsel == 1)
            Oh2[(((size_t)bb * H + h) * T + t) * HD + d] = (_Float16)v[r];
          else
            Oh3[(((size_t)bb * H + h) * HD + d) * T + t] = (_Float16)v[r];
        }
      } else if (MODE == 1 || MODE == 3) {
        const float bc = bias[col];
#pragma unroll
        for (int r = 0; r < 4; ++r)
          Of[(size_t)(row0 + r) * Ndim + col] =
              v[r] + bc + resid[(size_t)(row0 + r) * Ndim + col];
      } else {  // MODE 2: GELU -> fp16
        const float bc = bias[col];
#pragma unroll
        for (int r = 0; r < 4; ++r) {
          float t = v[r] + bc;
          t = 0.5f * t * (1.0f + erff(t * 0.70710678118654752f));
          Oh[(size_t)(row0 + r) * Ndim + col] = (_Float16)t;
        }
      }
    }
  }
}

// ---------------------------------------------------------------------------
// MFMA flash attention (causal). grid (T/64, B*H), 256 threads = 4 waves.
// Wave w owns q-rows [qt*64+w*16, +16). KVBLK=64, double-buffered K/Vt LDS.
// K LDS [kv][d] and Vt LDS [d][kv], both fp16 XOR-swizzled (chunk ^= row&7)
// via pre-swizzled global source feeding linear global_load_lds (rule 21).
// P is wave-private swizzled LDS (no barrier between write and read).
// Q (pre-scaled by 1/8) lives in registers as A-fragments.
// ---------------------------------------------------------------------------
__global__ __launch_bounds__(256) void attn_mfma(const _Float16* __restrict__ Qh,
                                                 const _Float16* __restrict__ Kh,
                                                 const _Float16* __restrict__ Vth,
                                                 _Float16* __restrict__ O) {
  __shared__ _Float16 Kb[2][64 * 64];
  __shared__ _Float16 Vb[2][64 * 64];
  __shared__ _Float16 Pb[64 * 64];
  const int tid = threadIdx.x;
  const int w = tid >> 6, l = tid & 63;
  const int lr = l & 15, lk = l >> 4;
  const int qt = blockIdx.x, bh = blockIdx.y;
  const int nt = qt + 1;
  const _Float16* Qg = Qh + (size_t)bh * T * HD;
  const _Float16* Kg = Kh + (size_t)bh * T * HD;
  const _Float16* Vg = Vth + (size_t)bh * HD * T;

  // Q A-fragments: row = l&15 (q), k = kk*32 + (l>>4)*8
  f16x8 qf[2];
#pragma unroll
  for (int kk = 0; kk < 2; ++kk)
    qf[kk] = *(const f16x8*)&Qg[(size_t)(qt * 64 + w * 16 + lr) * HD + kk * 32 + lk * 8];

  f32x4 acc[4] = {};  // O accumulator per d-tile; rows lk*4+r, col d=dt*16+lr
  float m_i[4], l_i[4];
#pragma unroll
  for (int r = 0; r < 4; ++r) { m_i[r] = -INFINITY; l_i[r] = 0.f; }

  const int srow = l >> 3;            // row within 8-row stage group
  const int schunk = (l & 7) ^ srow;  // pre-swizzled source chunk

  int buf = 0;
  // ---- stage tile 0 ----
#pragma unroll
  for (int i = 0; i < 2; ++i) {
    const int seg = w * 2 + i;
    const int rr = seg * 8 + srow;
    async_copy16(&Kb[0][seg * 512], Kg + (size_t)rr * HD + schunk * 8);
    async_copy16(&Vb[0][seg * 512], Vg + (size_t)rr * T + schunk * 8);
  }

  for (int kt = 0; kt < nt; ++kt) {
    __syncthreads();  // drains vmcnt -> tile kt ready; prev compute done
    if (kt + 1 < nt) {
#pragma unroll
      for (int i = 0; i < 2; ++i) {
        const int seg = w * 2 + i;
        const int rr = seg * 8 + srow;
        async_copy16(&Kb[buf ^ 1][seg * 512],
                     Kg + (size_t)((kt + 1) * 64 + rr) * HD + schunk * 8);
        async_copy16(&Vb[buf ^ 1][seg * 512],
                     Vg + (size_t)rr * T + (kt + 1) * 64 + schunk * 8);
      }
    }
    // ---- S = Q K^T (rows lk*4+r, col kv = ct*16+lr) ----
    f32x4 s[4] = {};
#pragma unroll
    for (int ct = 0; ct < 4; ++ct) {
#pragma unroll
      for (int kk = 0; kk < 2; ++kk) {
        const int row = ct * 16 + lr;
        const int ch = (kk * 4 + lk) ^ (row & 7);
        const f16x8 kf = *(const f16x8*)&Kb[buf][row * 64 + ch * 8];
        s[ct] = __builtin_amdgcn_mfma_f32_16x16x32_f16(qf[kk], kf, s[ct], 0, 0, 0);
      }
    }
    if (kt == qt) {  // causal mask on diagonal tile
#pragma unroll
      for (int ct = 0; ct < 4; ++ct)
#pragma unroll
        for (int r = 0; r < 4; ++r)
          if (ct * 16 + lr > w * 16 + lk * 4 + r) s[ct][r] = -INFINITY;
    }
    // ---- online softmax ----
    float alpha[4];
#pragma unroll
    for (int r = 0; r < 4; ++r) {
      float mx = fmaxf(fmaxf(s[0][r], s[1][r]), fmaxf(s[2][r], s[3][r]));
#pragma unroll
      for (int off = 1; off < 16; off <<= 1) mx = fmaxf(mx, __shfl_xor(mx, off, 16));
      const float mn = fmaxf(m_i[r], mx);
      alpha[r] = __expf(m_i[r] - mn);
      m_i[r] = mn;
    }
    float rs[4] = {0.f, 0.f, 0.f, 0.f};
    _Float16 ph[4][4];
#pragma unroll
    for (int ct = 0; ct < 4; ++ct)
#pragma unroll
      for (int r = 0; r < 4; ++r) {
        const float p = __expf(s[ct][r] - m_i[r]);
        rs[r] += p;
        ph[ct][r] = (_Float16)p;
      }
#pragma unroll
    for (int r = 0; r < 4; ++r) {
#pragma unroll
      for (int off = 1; off < 16; off <<= 1) rs[r] += __shfl_xor(rs[r], off, 16);
      l_i[r] = l_i[r] * alpha[r] + rs[r];
#pragma unroll
      for (int dt = 0; dt < 4; ++dt) acc[dt][r] *= alpha[r];
    }
    // ---- write P (wave-private rows w*16..+16, swizzled) ----
#pragma unroll
    for (int ct = 0; ct < 4; ++ct)
#pragma unroll
      for (int r = 0; r < 4; ++r) {
        const int q = w * 16 + lk * 4 + r;
        const int kv = ct * 16 + lr;
        Pb[q * 64 + (kv ^ ((q & 7) * 8))] = ph[ct][r];
      }
    // ---- O += P V ----
    const int qrow = w * 16 + lr;
#pragma unroll
    for (int kk = 0; kk < 2; ++kk) {
      const int pch = (kk * 4 + lk) ^ (qrow & 7);
      const f16x8 pa = *(const f16x8*)&Pb[qrow * 64 + pch * 8];
#pragma unroll
      for (int dt = 0; dt < 4; ++dt) {
        const int drow = dt * 16 + lr;
        const int vch = (kk * 4 + lk) ^ (drow & 7);
        const f16x8 vf = *(const f16x8*)&Vb[buf][drow * 64 + vch * 8];
        acc[dt] = __builtin_amdgcn_mfma_f32_16x16x32_f16(pa, vf, acc[dt], 0, 0, 0);
      }
    }
    buf ^= 1;
  }
  // ---- epilogue: normalize, write fp16 [b][t][h*64+d] ----
  const int bb = bh >> 4, h = bh & 15;
#pragma unroll
  for (int r = 0; r < 4; ++r) {
    const float inv = 1.0f / l_i[r];
    const int t = qt * 64 + w * 16 + lk * 4 + r;
#pragma unroll
    for (int dt = 0; dt < 4; ++dt)
      O[((size_t)bb * T + t) * C + h * 64 + dt * 16 + lr] = (_Float16)(acc[dt][r] * inv);
  }
}

// ---------------------------------------------------------------------------
extern "C" void kernel_launch(void* const* d_in, const int* in_sizes, int n_in,
                              void* d_out, int out_size, void* d_ws, size_t ws_size,
                              hipStream_t stream) {
  (void)in_sizes; (void)n_in; (void)out_size; (void)ws_size;
  const float* x   = (const float*)d_in[0];
  const float* Wq  = (const float*)d_in[1];
  const float* Wk  = (const float*)d_in[2];
  const float* Wv  = (const float*)d_in[3];
  const float* Wo  = (const float*)d_in[4];
  const float* bo  = (const float*)d_in[5];
  const float* g1  = (const float*)d_in[6];
  const float* be1 = (const float*)d_in[7];
  const float* g2  = (const float*)d_in[8];
  const float* be2 = (const float*)d_in[9];
  const float* W1  = (const float*)d_in[10];
  const float* b1  = (const float*)d_in[11];
  const float* W2  = (const float*)d_in[12];
  const float* b2  = (const float*)d_in[13];
  float* out = (float*)d_out;

  char* base = (char*)d_ws;
  _Float16* norm_h = (_Float16*)base;                    // 0..16 MB
  _Float16* WcatT  = (_Float16*)(base + (16ull << 20));  // 16..22 [3072][1024]
  _Float16* WoT    = (_Float16*)(base + (22ull << 20));  // 22..24 [1024][1024]
  _Float16* W1T    = (_Float16*)(base + (24ull << 20));  // 24..32 [4096][1024]
  _Float16* W2T    = (_Float16*)(base + (32ull << 20));  // 32..40 [1024][4096]
  _Float16* Qhb    = (_Float16*)(base + (40ull << 20));  // 40..56 [bh][t][d]
  _Float16* Khb    = (_Float16*)(base + (56ull << 20));  // 56..72 [bh][t][d]
  _Float16* Vthb   = (_Float16*)(base + (72ull << 20));  // 72..88 [bh][d][t]
  _Float16* attnCh = (_Float16*)(base + (88ull << 20));  // 88..104 [M][C]
  float* res       = (float*)(base + (104ull << 20));    // 104..136 fp32
  _Float16* hbuf   = (_Float16*)(base + (40ull << 20));  // 40..104, aliases QKV/attnC (dead)
  // total 136 MB

  tconv_qkv<<<dim3(16, 16, 3), 256, 0, stream>>>(Wq, Wk, Wv, WcatT);
  tconv<<<dim3(16, 16), 256, 0, stream>>>(Wo, WoT, C, C);
  tconv<<<dim3(64, 16), 256, 0, stream>>>(W1, W1T, C, F);
  tconv<<<dim3(16, 64), 256, 0, stream>>>(W2, W2T, F, C);

  ln_kernel<<<M, 256, 0, stream>>>(x, g1, be1, norm_h);
  mgemm<0><<<dim3(3072 / 128, M / 128), 256, 0, stream>>>(
      norm_h, WcatT, nullptr, nullptr, nullptr, Qhb, Khb, Vthb, 3072, C);
  attn_mfma<<<dim3(T / 64, Bsz * H), 256, 0, stream>>>(Qhb, Khb, Vthb, attnCh);
  mgemm<1><<<dim3(C / 128, M / 128), 256, 0, stream>>>(
      attnCh, WoT, bo, x, res, nullptr, nullptr, nullptr, C, C);
  ln_kernel<<<M, 256, 0, stream>>>(res, g2, be2, norm_h);
  mgemm<2><<<dim3(F / 128, M / 128), 256, 0, stream>>>(
      norm_h, W1T, b1, nullptr, nullptr, hbuf, nullptr, nullptr, F, C);
  mgemm<3><<<dim3(C / 128, M / 128), 256, 0, stream>>>(
      hbuf, W2T, b2, res, out, nullptr, nullptr, nullptr, C, F);
}

// Round 8
// 644.085 us; speedup vs baseline: 5.8960x; 1.1740x over previous
//
#include <hip/hip_runtime.h>
#include <math.h>

// Problem constants (DecoderLayer, fp32 in/out)
constexpr int Bsz = 4, T = 2048, C = 1024, H = 16, HD = 64, F = 4096;
constexpr int M = Bsz * T;  // 8192 rows
constexpr int NT = T / 64;  // 32 KV tiles

typedef _Float16 f16x8 __attribute__((ext_vector_type(8)));
typedef float f32x4 __attribute__((ext_vector_type(4)));
typedef unsigned int u32;

__device__ __forceinline__ void async_copy16(void* lds, const void* g) {
  __builtin_amdgcn_global_load_lds((const __attribute__((address_space(1))) u32*)g,
                                   (__attribute__((address_space(3))) u32*)lds, 16, 0, 0);
}

union H4 { _Float16 h[4]; uint2 u; };

// ---------------------------------------------------------------------------
// LayerNorm: one block per row (1024 floats), 256 threads * float4, fp16 out
// ---------------------------------------------------------------------------
__global__ __launch_bounds__(256) void ln_kernel(const float* __restrict__ x,
                                                 const float* __restrict__ g,
                                                 const float* __restrict__ b,
                                                 _Float16* __restrict__ outh) {
  const int row = blockIdx.x;
  const int tid = threadIdx.x;
  const float4 v = ((const float4*)(x + (size_t)row * C))[tid];
  float s = v.x + v.y + v.z + v.w;
  float ss = v.x * v.x + v.y * v.y + v.z * v.z + v.w * v.w;
#pragma unroll
  for (int off = 32; off > 0; off >>= 1) {
    s += __shfl_xor(s, off, 64);
    ss += __shfl_xor(ss, off, 64);
  }
  __shared__ float red[2][4];
  const int wv = tid >> 6;
  if ((tid & 63) == 0) { red[0][wv] = s; red[1][wv] = ss; }
  __syncthreads();
  s = red[0][0] + red[0][1] + red[0][2] + red[0][3];
  ss = red[1][0] + red[1][1] + red[1][2] + red[1][3];
  const float mu = s * (1.0f / C);
  const float var = ss * (1.0f / C) - mu * mu;
  const float rstd = rsqrtf(var + 1e-5f);
  const float4 gv = ((const float4*)g)[tid];
  const float4 bv = ((const float4*)b)[tid];
  H4 pk;
  pk.h[0] = (_Float16)((v.x - mu) * rstd * gv.x + bv.x);
  pk.h[1] = (_Float16)((v.y - mu) * rstd * gv.y + bv.y);
  pk.h[2] = (_Float16)((v.z - mu) * rstd * gv.z + bv.z);
  pk.h[3] = (_Float16)((v.w - mu) * rstd * gv.w + bv.w);
  ((uint2*)(outh + (size_t)row * C))[tid] = pk.u;
}

// ---------------------------------------------------------------------------
// Generic transpose+convert: W[K][N] fp32 -> WT[N][K] fp16. grid (N/64, K/64)
// ---------------------------------------------------------------------------
__global__ __launch_bounds__(256) void tconv(const float* __restrict__ W,
                                             _Float16* __restrict__ WT,
                                             int K, int N) {
  __shared__ float tile[64][65];
  const int tid = threadIdx.x;
  const int n0 = blockIdx.x * 64, k0 = blockIdx.y * 64;
#pragma unroll
  for (int i = 0; i < 4; ++i) {
    const int idx = i * 1024 + tid * 4;
    const int r = idx >> 6, c = idx & 63;
    const float4 v = *(const float4*)&W[(size_t)(k0 + r) * N + n0 + c];
    tile[r][c] = v.x; tile[r][c + 1] = v.y; tile[r][c + 2] = v.z; tile[r][c + 3] = v.w;
  }
  __syncthreads();
#pragma unroll
  for (int i = 0; i < 4; ++i) {
    const int idx = i * 1024 + tid * 4;
    const int r = idx >> 6, c = idx & 63;
    H4 pk;
#pragma unroll
    for (int j = 0; j < 4; ++j) pk.h[j] = (_Float16)tile[c + j][r];
    *(uint2*)&WT[(size_t)(n0 + r) * K + k0 + c] = pk.u;
  }
}

// ---------------------------------------------------------------------------
// QKV weights: Wq/Wk/Wv [16][1024][64] fp32 -> WcatT [3072][1024] fp16
// ---------------------------------------------------------------------------
__global__ __launch_bounds__(256) void tconv_qkv(const float* __restrict__ Wq,
                                                 const float* __restrict__ Wk,
                                                 const float* __restrict__ Wv,
                                                 _Float16* __restrict__ WcatT) {
  __shared__ float tile[64][65];
  const int tid = threadIdx.x;
  const int c0 = blockIdx.x * 64;
  const int h = blockIdx.y, wsel = blockIdx.z;
  const float* W = (wsel == 0 ? Wq : (wsel == 1 ? Wk : Wv)) + (size_t)h * C * HD;
  const int base_row = wsel * 1024 + h * 64;
#pragma unroll
  for (int i = 0; i < 4; ++i) {
    const int idx = i * 1024 + tid * 4;
    const int r = idx >> 6, c = idx & 63;
    const float4 v = *(const float4*)&W[(size_t)(c0 + r) * HD + c];
    tile[r][c] = v.x; tile[r][c + 1] = v.y; tile[r][c + 2] = v.z; tile[r][c + 3] = v.w;
  }
  __syncthreads();
#pragma unroll
  for (int i = 0; i < 4; ++i) {
    const int idx = i * 1024 + tid * 4;
    const int r = idx >> 6, c = idx & 63;
    H4 pk;
#pragma unroll
    for (int j = 0; j < 4; ++j) pk.h[j] = (_Float16)tile[c + j][r];
    *(uint2*)&WcatT[(size_t)(base_row + r) * C + c0 + c] = pk.u;
  }
}

// ---------------------------------------------------------------------------
// MFMA fp16 GEMM: C = A[M,K] @ B^T  (B stored [N][K] fp16)
// 128x128 tile, BK=64, 4 waves, mfma_f32_16x16x32_f16. XCD-swizzled block id.
// MODE 0: QKV  -> Qh fp16 (scaled log2e/8) [bh][t][d], Kh fp16 [bh][t][d],
//                 Vth fp16 transposed [bh][d][t]
// MODE 1: WO   -> +bias +resid, fp32 out
// MODE 2: FFN1 -> +bias, GELU, fp16 out
// MODE 3: FFN2 -> +bias +resid, fp32 out
// ---------------------------------------------------------------------------
template <int MODE>
__global__ __launch_bounds__(256) void mgemm(const _Float16* __restrict__ Ah,
                                             const _Float16* __restrict__ Bh,
                                             const float* __restrict__ bias,
                                             const float* __restrict__ resid,
                                             float* __restrict__ Of,
                                             _Float16* __restrict__ Oh,
                                             _Float16* __restrict__ Oh2,
                                             _Float16* __restrict__ Oh3,
                                             int Ndim, int Kdim) {
  __shared__ _Float16 Alds[128 * 64];
  __shared__ _Float16 Blds[128 * 64];
  const int tid = threadIdx.x;
  const int wv = tid >> 6, ln = tid & 63;
  const int wm = wv >> 1, wn = wv & 1;
  // XCD-aware swizzle (T1): bijective when nwg % 8 == 0 (all our grids are)
  int bx = blockIdx.x, by = blockIdx.y;
  {
    const int gx = gridDim.x;
    const int nwg = gx * gridDim.y;
    if ((nwg & 7) == 0) {
      int wg = by * gx + bx;
      wg = (wg & 7) * (nwg >> 3) + (wg >> 3);
      bx = wg % gx;
      by = wg / gx;
    }
  }
  const int m0 = by * 128, n0 = bx * 128;
  const int lr = ln & 15, lk = ln >> 4;

  const _Float16* Abase = Ah + (size_t)m0 * Kdim;
  const _Float16* Bbase = Bh + (size_t)n0 * Kdim;

  f32x4 acc[4][4] = {};

  for (int k0 = 0; k0 < Kdim; k0 += 64) {
    __syncthreads();
#pragma unroll
    for (int i = 0; i < 4; ++i) {
      const int seg = wv * 4 + i;
      const int row = seg * 8 + (ln >> 3);
      async_copy16(Alds + seg * 512, Abase + (size_t)row * Kdim + k0 + (ln & 7) * 8);
      async_copy16(Blds + seg * 512, Bbase + (size_t)row * Kdim + k0 + (ln & 7) * 8);
    }
    __syncthreads();
#pragma unroll
    for (int kk = 0; kk < 2; ++kk) {
      f16x8 af[4], bf[4];
#pragma unroll
      for (int fm = 0; fm < 4; ++fm)
        af[fm] = *(const f16x8*)&Alds[(wm * 64 + fm * 16 + lr) * 64 + kk * 32 + lk * 8];
#pragma unroll
      for (int fn = 0; fn < 4; ++fn)
        bf[fn] = *(const f16x8*)&Blds[(wn * 64 + fn * 16 + lr) * 64 + kk * 32 + lk * 8];
      __builtin_amdgcn_s_setprio(1);
#pragma unroll
      for (int fm = 0; fm < 4; ++fm)
#pragma unroll
        for (int fn = 0; fn < 4; ++fn)
          acc[fm][fn] = __builtin_amdgcn_mfma_f32_16x16x32_f16(af[fm], bf[fn], acc[fm][fn], 0, 0, 0);
      __builtin_amdgcn_s_setprio(0);
    }
  }

  // Epilogue. D layout: col = ln&15, row = (ln>>4)*4 + r
#pragma unroll
  for (int fm = 0; fm < 4; ++fm) {
#pragma unroll
    for (int fn = 0; fn < 4; ++fn) {
      const int row0 = m0 + wm * 64 + fm * 16 + lk * 4;
      const int col = n0 + wn * 64 + fn * 16 + lr;
      const f32x4 v = acc[fm][fn];
      if (MODE == 0) {
        const int wsel = col >> 10, h = (col >> 6) & 15, d = col & 63;
#pragma unroll
        for (int r = 0; r < 4; ++r) {
          const int m = row0 + r;
          const int bb = m >> 11, t = m & (T - 1);
          if (wsel == 0)  // fold 1/sqrt(64) * log2(e) so attention works in exp2 domain
            Oh[(((size_t)bb * H + h) * T + t) * HD + d] = (_Float16)(v[r] * 0.18033688011112042f);
          else if (wsel == 1)
            Oh2[(((size_t)bb * H + h) * T + t) * HD + d] = (_Float16)v[r];
          else
            Oh3[(((size_t)bb * H + h) * HD + d) * T + t] = (_Float16)v[r];
        }
      } else if (MODE == 1 || MODE == 3) {
        const float bc = bias[col];
#pragma unroll
        for (int r = 0; r < 4; ++r)
          Of[(size_t)(row0 + r) * Ndim + col] =
              v[r] + bc + resid[(size_t)(row0 + r) * Ndim + col];
      } else {  // MODE 2: GELU -> fp16
        const float bc = bias[col];
#pragma unroll
        for (int r = 0; r < 4; ++r) {
          float t = v[r] + bc;
          t = 0.5f * t * (1.0f + erff(t * 0.70710678118654752f));
          Oh[(size_t)(row0 + r) * Ndim + col] = (_Float16)t;
        }
      }
    }
  }
}

// ---------------------------------------------------------------------------
// Attention helpers (16x16x32 MFMA; A/B row=l&15,k=(l>>4)*8+j; D col=l&15,
// row=(l>>4)*4+r). Scores arrive pre-scaled by log2e/8 -> exp2 softmax.
// ---------------------------------------------------------------------------
__device__ __forceinline__ void qkt_tile(const f16x8 (&qf)[2],
                                         const _Float16* __restrict__ Kbuf,
                                         f32x4 (&s)[4], int lr, int lk) {
  __builtin_amdgcn_s_setprio(1);
#pragma unroll
  for (int ct = 0; ct < 4; ++ct) {
    s[ct] = f32x4{0.f, 0.f, 0.f, 0.f};
#pragma unroll
    for (int kk = 0; kk < 2; ++kk) {
      const int row = ct * 16 + lr;
      const int ch = (kk * 4 + lk) ^ (row & 7);
      const f16x8 kf = *(const f16x8*)&Kbuf[row * 64 + ch * 8];
      s[ct] = __builtin_amdgcn_mfma_f32_16x16x32_f16(qf[kk], kf, s[ct], 0, 0, 0);
    }
  }
  __builtin_amdgcn_s_setprio(0);
}

__device__ __forceinline__ void online_sm(f32x4 (&s)[4], float (&m_i)[4], float (&l_i)[4],
                                          f32x4 (&acc)[4], _Float16 (&ph)[4][4]) {
  float alpha[4];
#pragma unroll
  for (int r = 0; r < 4; ++r) {
    float mx = fmaxf(fmaxf(s[0][r], s[1][r]), fmaxf(s[2][r], s[3][r]));
#pragma unroll
    for (int off = 1; off < 16; off <<= 1) mx = fmaxf(mx, __shfl_xor(mx, off, 16));
    const float mn = fmaxf(m_i[r], mx);
    alpha[r] = exp2f(m_i[r] - mn);
    m_i[r] = mn;
  }
  float rs[4] = {0.f, 0.f, 0.f, 0.f};
#pragma unroll
  for (int ct = 0; ct < 4; ++ct)
#pragma unroll
    for (int r = 0; r < 4; ++r) {
      const float p = exp2f(s[ct][r] - m_i[r]);
      rs[r] += p;
      ph[ct][r] = (_Float16)p;
    }
#pragma unroll
  for (int r = 0; r < 4; ++r) {
#pragma unroll
    for (int off = 1; off < 16; off <<= 1) rs[r] += __shfl_xor(rs[r], off, 16);
    l_i[r] = l_i[r] * alpha[r] + rs[r];
#pragma unroll
    for (int dt = 0; dt < 4; ++dt) acc[dt][r] *= alpha[r];
  }
}

__device__ __forceinline__ void pv_tile(const _Float16 (&ph)[4][4], _Float16* Pb,
                                        const _Float16* __restrict__ Vbuf,
                                        f32x4 (&acc)[4], int w, int lr, int lk) {
  // write P (wave-private rows w*16..+16, swizzled)
#pragma unroll
  for (int ct = 0; ct < 4; ++ct)
#pragma unroll
    for (int r = 0; r < 4; ++r) {
      const int q = w * 16 + lk * 4 + r;
      const int kv = ct * 16 + lr;
      Pb[q * 64 + (kv ^ ((q & 7) * 8))] = ph[ct][r];
    }
  const int qrow = w * 16 + lr;
  __builtin_amdgcn_s_setprio(1);
#pragma unroll
  for (int kk = 0; kk < 2; ++kk) {
    const int pch = (kk * 4 + lk) ^ (qrow & 7);
    const f16x8 pa = *(const f16x8*)&Pb[qrow * 64 + pch * 8];
#pragma unroll
    for (int dt = 0; dt < 4; ++dt) {
      const int drow = dt * 16 + lr;
      const int vch = (kk * 4 + lk) ^ (drow & 7);
      const f16x8 vf = *(const f16x8*)&Vbuf[drow * 64 + vch * 8];
      acc[dt] = __builtin_amdgcn_mfma_f32_16x16x32_f16(pa, vf, acc[dt], 0, 0, 0);
    }
  }
  __builtin_amdgcn_s_setprio(0);
}

// ---------------------------------------------------------------------------
// MFMA flash attention (causal), PAIRED q-tiles for load balance.
// grid (NT/2=16, B*H), 256 threads = 4 waves. Block b owns q-tiles
// {b, NT-1-b} -> every block computes exactly NT+1 tile-products.
// K/V staged once per kt serve both q-tiles. LDS 40KB -> 4 blocks/CU.
// ---------------------------------------------------------------------------
__global__ __launch_bounds__(256) void attn_mfma(const _Float16* __restrict__ Qh,
                                                 const _Float16* __restrict__ Kh,
                                                 const _Float16* __restrict__ Vth,
                                                 _Float16* __restrict__ O) {
  __shared__ _Float16 Kb[2][64 * 64];
  __shared__ _Float16 Vb[2][64 * 64];
  __shared__ _Float16 Pb[64 * 64];
  const int tid = threadIdx.x;
  const int w = tid >> 6, l = tid & 63;
  const int lr = l & 15, lk = l >> 4;
  const int qlo = blockIdx.x, qhi = (NT - 1) - blockIdx.x;
  const int bh = blockIdx.y;
  const _Float16* Qg = Qh + (size_t)bh * T * HD;
  const _Float16* Kg = Kh + (size_t)bh * T * HD;
  const _Float16* Vg = Vth + (size_t)bh * HD * T;

  f16x8 qfl[2], qfh[2];
#pragma unroll
  for (int kk = 0; kk < 2; ++kk) {
    qfl[kk] = *(const f16x8*)&Qg[(size_t)(qlo * 64 + w * 16 + lr) * HD + kk * 32 + lk * 8];
    qfh[kk] = *(const f16x8*)&Qg[(size_t)(qhi * 64 + w * 16 + lr) * HD + kk * 32 + lk * 8];
  }

  f32x4 accl[4] = {}, acch[4] = {};
  float ml[4], ll[4], mh[4], lh[4];
#pragma unroll
  for (int r = 0; r < 4; ++r) {
    ml[r] = -INFINITY; ll[r] = 0.f;
    mh[r] = -INFINITY; lh[r] = 0.f;
  }

  const int srow = l >> 3;            // row within 8-row stage group
  const int schunk = (l & 7) ^ srow;  // pre-swizzled source chunk

  int buf = 0;
  // ---- stage tile 0 ----
#pragma unroll
  for (int i = 0; i < 2; ++i) {
    const int seg = w * 2 + i;
    const int rr = seg * 8 + srow;
    async_copy16(&Kb[0][seg * 512], Kg + (size_t)rr * HD + schunk * 8);
    async_copy16(&Vb[0][seg * 512], Vg + (size_t)rr * T + schunk * 8);
  }

  for (int kt = 0; kt <= qhi; ++kt) {
    __syncthreads();  // drains vmcnt -> tile kt ready; prev compute done
    if (kt < qhi) {
#pragma unroll
      for (int i = 0; i < 2; ++i) {
        const int seg = w * 2 + i;
        const int rr = seg * 8 + srow;
        async_copy16(&Kb[buf ^ 1][seg * 512],
                     Kg + (size_t)((kt + 1) * 64 + rr) * HD + schunk * 8);
        async_copy16(&Vb[buf ^ 1][seg * 512],
                     Vg + (size_t)rr * T + (kt + 1) * 64 + schunk * 8);
      }
    }
    f32x4 s[4];
    _Float16 ph[4][4];
    // ---- HI q-tile (always active) ----
    qkt_tile(qfh, &Kb[buf][0], s, lr, lk);
    if (kt == qhi) {
#pragma unroll
      for (int ct = 0; ct < 4; ++ct)
#pragma unroll
        for (int r = 0; r < 4; ++r)
          if (ct * 16 + lr > w * 16 + lk * 4 + r) s[ct][r] = -INFINITY;
    }
    online_sm(s, mh, lh, acch, ph);
    pv_tile(ph, &Pb[0], &Vb[buf][0], acch, w, lr, lk);
    // ---- LO q-tile (active for kt <= qlo; wave-uniform branch) ----
    if (kt <= qlo) {
      qkt_tile(qfl, &Kb[buf][0], s, lr, lk);
      if (kt == qlo) {
#pragma unroll
        for (int ct = 0; ct < 4; ++ct)
#pragma unroll
          for (int r = 0; r < 4; ++r)
            if (ct * 16 + lr > w * 16 + lk * 4 + r) s[ct][r] = -INFINITY;
      }
      online_sm(s, ml, ll, accl, ph);
      pv_tile(ph, &Pb[0], &Vb[buf][0], accl, w, lr, lk);
    }
    buf ^= 1;
  }
  // ---- epilogue: normalize, write fp16 [b][t][h*64+d] ----
  const int bb = bh >> 4, h = bh & 15;
#pragma unroll
  for (int r = 0; r < 4; ++r) {
    const float invh = 1.0f / lh[r];
    const int th = qhi * 64 + w * 16 + lk * 4 + r;
#pragma unroll
    for (int dt = 0; dt < 4; ++dt)
      O[((size_t)bb * T + th) * C + h * 64 + dt * 16 + lr] = (_Float16)(acch[dt][r] * invh);
    const float invl = 1.0f / ll[r];
    const int tl = qlo * 64 + w * 16 + lk * 4 + r;
#pragma unroll
    for (int dt = 0; dt < 4; ++dt)
      O[((size_t)bb * T + tl) * C + h * 64 + dt * 16 + lr] = (_Float16)(accl[dt][r] * invl);
  }
}

// ---------------------------------------------------------------------------
extern "C" void kernel_launch(void* const* d_in, const int* in_sizes, int n_in,
                              void* d_out, int out_size, void* d_ws, size_t ws_size,
                              hipStream_t stream) {
  (void)in_sizes; (void)n_in; (void)out_size; (void)ws_size;
  const float* x   = (const float*)d_in[0];
  const float* Wq  = (const float*)d_in[1];
  const float* Wk  = (const float*)d_in[2];
  const float* Wv  = (const float*)d_in[3];
  const float* Wo  = (const float*)d_in[4];
  const float* bo  = (const float*)d_in[5];
  const float* g1  = (const float*)d_in[6];
  const float* be1 = (const float*)d_in[7];
  const float* g2  = (const float*)d_in[8];
  const float* be2 = (const float*)d_in[9];
  const float* W1  = (const float*)d_in[10];
  const float* b1  = (const float*)d_in[11];
  const float* W2  = (const float*)d_in[12];
  const float* b2  = (const float*)d_in[13];
  float* out = (float*)d_out;

  char* base = (char*)d_ws;
  _Float16* norm_h = (_Float16*)base;                    // 0..16 MB
  _Float16* WcatT  = (_Float16*)(base + (16ull << 20));  // 16..22 [3072][1024]
  _Float16* WoT    = (_Float16*)(base + (22ull << 20));  // 22..24 [1024][1024]
  _Float16* W1T    = (_Float16*)(base + (24ull << 20));  // 24..32 [4096][1024]
  _Float16* W2T    = (_Float16*)(base + (32ull << 20));  // 32..40 [1024][4096]
  _Float16* Qhb    = (_Float16*)(base + (40ull << 20));  // 40..56 [bh][t][d]
  _Float16* Khb    = (_Float16*)(base + (56ull << 20));  // 56..72 [bh][t][d]
  _Float16* Vthb   = (_Float16*)(base + (72ull << 20));  // 72..88 [bh][d][t]
  _Float16* attnCh = (_Float16*)(base + (88ull << 20));  // 88..104 [M][C]
  float* res       = (float*)(base + (104ull << 20));    // 104..136 fp32
  _Float16* hbuf   = (_Float16*)(base + (40ull << 20));  // 40..104, aliases QKV/attnC (dead)
  // total 136 MB

  tconv_qkv<<<dim3(16, 16, 3), 256, 0, stream>>>(Wq, Wk, Wv, WcatT);
  tconv<<<dim3(16, 16), 256, 0, stream>>>(Wo, WoT, C, C);
  tconv<<<dim3(64, 16), 256, 0, stream>>>(W1, W1T, C, F);
  tconv<<<dim3(16, 64), 256, 0, stream>>>(W2, W2T, F, C);

  ln_kernel<<<M, 256, 0, stream>>>(x, g1, be1, norm_h);
  mgemm<0><<<dim3(3072 / 128, M / 128), 256, 0, stream>>>(
      norm_h, WcatT, nullptr, nullptr, nullptr, Qhb, Khb, Vthb, 3072, C);
  attn_mfma<<<dim3(NT / 2, Bsz * H), 256, 0, stream>>>(Qhb, Khb, Vthb, attnCh);
  mgemm<1><<<dim3(C / 128, M / 128), 256, 0, stream>>>(
      attnCh, WoT, bo, x, res, nullptr, nullptr, nullptr, C, C);
  ln_kernel<<<M, 256, 0, stream>>>(res, g2, be2, norm_h);
  mgemm<2><<<dim3(F / 128, M / 128), 256, 0, stream>>>(
      norm_h, W1T, b1, nullptr, nullptr, hbuf, nullptr, nullptr, F, C);
  mgemm<3><<<dim3(C / 128, M / 128), 256, 0, stream>>>(
      hbuf, W2T, b2, res, out, nullptr, nullptr, nullptr, C, F);
}

// Round 10
// 616.028 us; speedup vs baseline: 6.1645x; 1.0455x over previous
//
#include <hip/hip_runtime.h>
#include <math.h>

// Problem constants (DecoderLayer, fp32 in/out)
constexpr int Bsz = 4, T = 2048, C = 1024, H = 16, HD = 64, F = 4096;
constexpr int M = Bsz * T;  // 8192 rows
constexpr int NT = T / 64;  // 32 KV tiles

typedef _Float16 f16x8 __attribute__((ext_vector_type(8)));
typedef float f32x4 __attribute__((ext_vector_type(4)));
typedef unsigned int u32;

__device__ __forceinline__ void async_copy16(void* lds, const void* g) {
  __builtin_amdgcn_global_load_lds((const __attribute__((address_space(1))) u32*)g,
                                   (__attribute__((address_space(3))) u32*)lds, 16, 0, 0);
}

union H4 { _Float16 h[4]; uint2 u; };

// ---------------------------------------------------------------------------
// LayerNorm: one block per row (1024 floats), 256 threads * float4, fp16 out
// ---------------------------------------------------------------------------
__global__ __launch_bounds__(256) void ln_kernel(const float* __restrict__ x,
                                                 const float* __restrict__ g,
                                                 const float* __restrict__ b,
                                                 _Float16* __restrict__ outh) {
  const int row = blockIdx.x;
  const int tid = threadIdx.x;
  const float4 v = ((const float4*)(x + (size_t)row * C))[tid];
  float s = v.x + v.y + v.z + v.w;
  float ss = v.x * v.x + v.y * v.y + v.z * v.z + v.w * v.w;
#pragma unroll
  for (int off = 32; off > 0; off >>= 1) {
    s += __shfl_xor(s, off, 64);
    ss += __shfl_xor(ss, off, 64);
  }
  __shared__ float red[2][4];
  const int wv = tid >> 6;
  if ((tid & 63) == 0) { red[0][wv] = s; red[1][wv] = ss; }
  __syncthreads();
  s = red[0][0] + red[0][1] + red[0][2] + red[0][3];
  ss = red[1][0] + red[1][1] + red[1][2] + red[1][3];
  const float mu = s * (1.0f / C);
  const float var = ss * (1.0f / C) - mu * mu;
  const float rstd = rsqrtf(var + 1e-5f);
  const float4 gv = ((const float4*)g)[tid];
  const float4 bv = ((const float4*)b)[tid];
  H4 pk;
  pk.h[0] = (_Float16)((v.x - mu) * rstd * gv.x + bv.x);
  pk.h[1] = (_Float16)((v.y - mu) * rstd * gv.y + bv.y);
  pk.h[2] = (_Float16)((v.z - mu) * rstd * gv.z + bv.z);
  pk.h[3] = (_Float16)((v.w - mu) * rstd * gv.w + bv.w);
  ((uint2*)(outh + (size_t)row * C))[tid] = pk.u;
}

// ---------------------------------------------------------------------------
// Generic transpose+convert: W[K][N] fp32 -> WT[N][K] fp16. grid (N/64, K/64)
// ---------------------------------------------------------------------------
__global__ __launch_bounds__(256) void tconv(const float* __restrict__ W,
                                             _Float16* __restrict__ WT,
                                             int K, int N) {
  __shared__ float tile[64][65];
  const int tid = threadIdx.x;
  const int n0 = blockIdx.x * 64, k0 = blockIdx.y * 64;
#pragma unroll
  for (int i = 0; i < 4; ++i) {
    const int idx = i * 1024 + tid * 4;
    const int r = idx >> 6, c = idx & 63;
    const float4 v = *(const float4*)&W[(size_t)(k0 + r) * N + n0 + c];
    tile[r][c] = v.x; tile[r][c + 1] = v.y; tile[r][c + 2] = v.z; tile[r][c + 3] = v.w;
  }
  __syncthreads();
#pragma unroll
  for (int i = 0; i < 4; ++i) {
    const int idx = i * 1024 + tid * 4;
    const int r = idx >> 6, c = idx & 63;
    H4 pk;
#pragma unroll
    for (int j = 0; j < 4; ++j) pk.h[j] = (_Float16)tile[c + j][r];
    *(uint2*)&WT[(size_t)(n0 + r) * K + k0 + c] = pk.u;
  }
}

// ---------------------------------------------------------------------------
// QKV weights: Wq/Wk/Wv [16][1024][64] fp32 -> WcatT [3072][1024] fp16
// ---------------------------------------------------------------------------
__global__ __launch_bounds__(256) void tconv_qkv(const float* __restrict__ Wq,
                                                 const float* __restrict__ Wk,
                                                 const float* __restrict__ Wv,
                                                 _Float16* __restrict__ WcatT) {
  __shared__ float tile[64][65];
  const int tid = threadIdx.x;
  const int c0 = blockIdx.x * 64;
  const int h = blockIdx.y, wsel = blockIdx.z;
  const float* W = (wsel == 0 ? Wq : (wsel == 1 ? Wk : Wv)) + (size_t)h * C * HD;
  const int base_row = wsel * 1024 + h * 64;
#pragma unroll
  for (int i = 0; i < 4; ++i) {
    const int idx = i * 1024 + tid * 4;
    const int r = idx >> 6, c = idx & 63;
    const float4 v = *(const float4*)&W[(size_t)(c0 + r) * HD + c];
    tile[r][c] = v.x; tile[r][c + 1] = v.y; tile[r][c + 2] = v.z; tile[r][c + 3] = v.w;
  }
  __syncthreads();
#pragma unroll
  for (int i = 0; i < 4; ++i) {
    const int idx = i * 1024 + tid * 4;
    const int r = idx >> 6, c = idx & 63;
    H4 pk;
#pragma unroll
    for (int j = 0; j < 4; ++j) pk.h[j] = (_Float16)tile[c + j][r];
    *(uint2*)&WcatT[(size_t)(base_row + r) * C + c0 + c] = pk.u;
  }
}

// ---------------------------------------------------------------------------
// MFMA fp16 GEMM: C = A[M,K] @ B^T  (B stored [N][K] fp16)
// 128x128 tile, BK=64, 4 waves, mfma_f32_16x16x32_f16. XCD-swizzled block id.
// MODE 0: QKV  -> Qh fp16 (scaled log2e/8) [bh][t][d], Kh fp16 [bh][t][d],
//                 Vth fp16 transposed [bh][d][t]
// MODE 1: WO   -> +bias +resid, fp32 out
// MODE 2: FFN1 -> +bias, GELU, fp16 out
// MODE 3: FFN2 -> +bias +resid, fp32 out
// ---------------------------------------------------------------------------
template <int MODE>
__global__ __launch_bounds__(256) void mgemm(const _Float16* __restrict__ Ah,
                                             const _Float16* __restrict__ Bh,
                                             const float* __restrict__ bias,
                                             const float* __restrict__ resid,
                                             float* __restrict__ Of,
                                             _Float16* __restrict__ Oh,
                                             _Float16* __restrict__ Oh2,
                                             _Float16* __restrict__ Oh3,
                                             int Ndim, int Kdim) {
  __shared__ _Float16 Alds[128 * 64];
  __shared__ _Float16 Blds[128 * 64];
  const int tid = threadIdx.x;
  const int wv = tid >> 6, ln = tid & 63;
  const int wm = wv >> 1, wn = wv & 1;
  // XCD-aware swizzle (T1): bijective when nwg % 8 == 0 (all our grids are)
  int bx = blockIdx.x, by = blockIdx.y;
  {
    const int gx = gridDim.x;
    const int nwg = gx * gridDim.y;
    if ((nwg & 7) == 0) {
      int wg = by * gx + bx;
      wg = (wg & 7) * (nwg >> 3) + (wg >> 3);
      bx = wg % gx;
      by = wg / gx;
    }
  }
  const int m0 = by * 128, n0 = bx * 128;
  const int lr = ln & 15, lk = ln >> 4;

  const _Float16* Abase = Ah + (size_t)m0 * Kdim;
  const _Float16* Bbase = Bh + (size_t)n0 * Kdim;

  f32x4 acc[4][4] = {};

  for (int k0 = 0; k0 < Kdim; k0 += 64) {
    __syncthreads();
#pragma unroll
    for (int i = 0; i < 4; ++i) {
      const int seg = wv * 4 + i;
      const int row = seg * 8 + (ln >> 3);
      async_copy16(Alds + seg * 512, Abase + (size_t)row * Kdim + k0 + (ln & 7) * 8);
      async_copy16(Blds + seg * 512, Bbase + (size_t)row * Kdim + k0 + (ln & 7) * 8);
    }
    __syncthreads();
#pragma unroll
    for (int kk = 0; kk < 2; ++kk) {
      f16x8 af[4], bf[4];
#pragma unroll
      for (int fm = 0; fm < 4; ++fm)
        af[fm] = *(const f16x8*)&Alds[(wm * 64 + fm * 16 + lr) * 64 + kk * 32 + lk * 8];
#pragma unroll
      for (int fn = 0; fn < 4; ++fn)
        bf[fn] = *(const f16x8*)&Blds[(wn * 64 + fn * 16 + lr) * 64 + kk * 32 + lk * 8];
      __builtin_amdgcn_s_setprio(1);
#pragma unroll
      for (int fm = 0; fm < 4; ++fm)
#pragma unroll
        for (int fn = 0; fn < 4; ++fn)
          acc[fm][fn] = __builtin_amdgcn_mfma_f32_16x16x32_f16(af[fm], bf[fn], acc[fm][fn], 0, 0, 0);
      __builtin_amdgcn_s_setprio(0);
    }
  }

  // Epilogue. D layout: col = ln&15, row = (ln>>4)*4 + r
#pragma unroll
  for (int fm = 0; fm < 4; ++fm) {
#pragma unroll
    for (int fn = 0; fn < 4; ++fn) {
      const int row0 = m0 + wm * 64 + fm * 16 + lk * 4;
      const int col = n0 + wn * 64 + fn * 16 + lr;
      const f32x4 v = acc[fm][fn];
      if (MODE == 0) {
        const int wsel = col >> 10, h = (col >> 6) & 15, d = col & 63;
#pragma unroll
        for (int r = 0; r < 4; ++r) {
          const int m = row0 + r;
          const int bb = m >> 11, t = m & (T - 1);
          if (wsel == 0)  // fold 1/sqrt(64) * log2(e) so attention works in exp2 domain
            Oh[(((size_t)bb * H + h) * T + t) * HD + d] = (_Float16)(v[r] * 0.18033688011112042f);
          else if (wsel == 1)
            Oh2[(((size_t)bb * H + h) * T + t) * HD + d] = (_Float16)v[r];
          else
            Oh3[(((size_t)bb * H + h) * HD + d) * T + t] = (_Float16)v[r];
        }
      } else if (MODE == 1 || MODE == 3) {
        const float bc = bias[col];
#pragma unroll
        for (int r = 0; r < 4; ++r)
          Of[(size_t)(row0 + r) * Ndim + col] =
              v[r] + bc + resid[(size_t)(row0 + r) * Ndim + col];
      } else {  // MODE 2: GELU -> fp16
        const float bc = bias[col];
#pragma unroll
        for (int r = 0; r < 4; ++r) {
          float t = v[r] + bc;
          t = 0.5f * t * (1.0f + erff(t * 0.70710678118654752f));
          Oh[(size_t)(row0 + r) * Ndim + col] = (_Float16)t;
        }
      }
    }
  }
}

// ---------------------------------------------------------------------------
// Attention helpers. SWAPPED QK^T: compute mfma(K,Q) so D[kv][q] with
// q = col = l&15 -> each lane holds 16 kv-scores for ONE q in registers.
// Row-reduce = in-register tree + 2 shfl_xor (x16, x32). Scores pre-scaled
// by log2e/8 -> exp2 softmax. T13 defer-max (THR=8, P bounded by 2^8).
// ---------------------------------------------------------------------------
__device__ __forceinline__ void qkt_tile(const f16x8 (&qf)[2],
                                         const _Float16* __restrict__ Kbuf,
                                         f32x4 (&s)[4], int lr, int lk) {
  __builtin_amdgcn_s_setprio(1);
#pragma unroll
  for (int ct = 0; ct < 4; ++ct) {
    s[ct] = f32x4{0.f, 0.f, 0.f, 0.f};
#pragma unroll
    for (int kk = 0; kk < 2; ++kk) {
      const int row = ct * 16 + lr;
      const int ch = (kk * 4 + lk) ^ (row & 7);
      const f16x8 kf = *(const f16x8*)&Kbuf[row * 64 + ch * 8];
      s[ct] = __builtin_amdgcn_mfma_f32_16x16x32_f16(kf, qf[kk], s[ct], 0, 0, 0);
    }
  }
  __builtin_amdgcn_s_setprio(0);
}

// s[ct][r] = S[kv_local = ct*16 + lk*4 + r][q_local = lr], per-lane stats for q=lr
__device__ __forceinline__ void online_sm(const f32x4 (&s)[4], float& m_i, float& l_i,
                                          f32x4 (&acc)[4], _Float16 (&ph)[4][4], int l) {
  float mx = fmaxf(fmaxf(s[0][0], s[0][1]), fmaxf(s[0][2], s[0][3]));
#pragma unroll
  for (int ct = 1; ct < 4; ++ct)
    mx = fmaxf(mx, fmaxf(fmaxf(s[ct][0], s[ct][1]), fmaxf(s[ct][2], s[ct][3])));
  mx = fmaxf(mx, __shfl_xor(mx, 16, 64));
  mx = fmaxf(mx, __shfl_xor(mx, 32, 64));
  float mn = fmaxf(m_i, mx);
  if (__all(mx - m_i <= 8.0f)) {
    mn = m_i;  // defer: keep old max; P values bounded by 2^8 (fp16-safe)
  } else {
    const float alpha = exp2f(m_i - mn);
    m_i = mn;
    l_i *= alpha;
    // gather alpha for this thread's 4 accumulator q-rows (q' = (l>>4)*4+r)
#pragma unroll
    for (int r = 0; r < 4; ++r) {
      const float a_r = __shfl(alpha, (l & 48) | (((l >> 4) & 3) * 4 + r), 64);
#pragma unroll
      for (int dt = 0; dt < 4; ++dt) acc[dt][r] *= a_r;
    }
  }
  float rs = 0.f;
#pragma unroll
  for (int ct = 0; ct < 4; ++ct)
#pragma unroll
    for (int r = 0; r < 4; ++r) {
      const float p = exp2f(s[ct][r] - mn);
      rs += p;
      ph[ct][r] = (_Float16)p;
    }
  rs += __shfl_xor(rs, 16, 64);
  rs += __shfl_xor(rs, 32, 64);
  l_i += rs;
}

__device__ __forceinline__ void pv_tile(const _Float16 (&ph)[4][4], _Float16* Pb,
                                        const _Float16* __restrict__ Vbuf,
                                        f32x4 (&acc)[4], int w, int lr, int lk) {
  // write P (swapped layout: lane holds P[kv=ct*16+lk*4+r][q=lr]) to rows q
  const int qw = w * 16 + lr;
#pragma unroll
  for (int ct = 0; ct < 4; ++ct)
#pragma unroll
    for (int r = 0; r < 4; ++r) {
      const int kv = ct * 16 + lk * 4 + r;
      Pb[qw * 64 + (kv ^ ((qw & 7) * 8))] = ph[ct][r];
    }
  __builtin_amdgcn_s_setprio(1);
#pragma unroll
  for (int kk = 0; kk < 2; ++kk) {
    const int pch = (kk * 4 + lk) ^ (qw & 7);
    const f16x8 pa = *(const f16x8*)&Pb[qw * 64 + pch * 8];
#pragma unroll
    for (int dt = 0; dt < 4; ++dt) {
      const int drow = dt * 16 + lr;
      const int vch = (kk * 4 + lk) ^ (drow & 7);
      const f16x8 vf = *(const f16x8*)&Vbuf[drow * 64 + vch * 8];
      acc[dt] = __builtin_amdgcn_mfma_f32_16x16x32_f16(pa, vf, acc[dt], 0, 0, 0);
    }
  }
  __builtin_amdgcn_s_setprio(0);
}

// ---------------------------------------------------------------------------
// MFMA flash attention (causal), PAIRED q-tiles for load balance.
// grid (NT/2=16, B*H), 256 threads = 4 waves. Block b owns q-tiles
// {b, NT-1-b} -> every block computes exactly NT+1 tile-products.
// K/V staged once per kt serve both q-tiles. LDS 40KB -> 4 blocks/CU.
// ---------------------------------------------------------------------------
__global__ __launch_bounds__(256) void attn_mfma(const _Float16* __restrict__ Qh,
                                                 const _Float16* __restrict__ Kh,
                                                 const _Float16* __restrict__ Vth,
                                                 _Float16* __restrict__ O) {
  __shared__ _Float16 Kb[2][64 * 64];
  __shared__ _Float16 Vb[2][64 * 64];
  __shared__ _Float16 Pb[64 * 64];
  const int tid = threadIdx.x;
  const int w = tid >> 6, l = tid & 63;
  const int lr = l & 15, lk = l >> 4;
  const int qlo = blockIdx.x, qhi = (NT - 1) - blockIdx.x;
  const int bh = blockIdx.y;
  const _Float16* Qg = Qh + (size_t)bh * T * HD;
  const _Float16* Kg = Kh + (size_t)bh * T * HD;
  const _Float16* Vg = Vth + (size_t)bh * HD * T;

  f16x8 qfl[2], qfh[2];
#pragma unroll
  for (int kk = 0; kk < 2; ++kk) {
    qfl[kk] = *(const f16x8*)&Qg[(size_t)(qlo * 64 + w * 16 + lr) * HD + kk * 32 + lk * 8];
    qfh[kk] = *(const f16x8*)&Qg[(size_t)(qhi * 64 + w * 16 + lr) * HD + kk * 32 + lk * 8];
  }

  f32x4 accl[4] = {}, acch[4] = {};
  float ml = -INFINITY, ll = 0.f, mh = -INFINITY, lh = 0.f;  // per-lane stats for q=lr

  const int srow = l >> 3;            // row within 8-row stage group
  const int schunk = (l & 7) ^ srow;  // pre-swizzled source chunk

  int buf = 0;
  // ---- stage tile 0 ----
#pragma unroll
  for (int i = 0; i < 2; ++i) {
    const int seg = w * 2 + i;
    const int rr = seg * 8 + srow;
    async_copy16(&Kb[0][seg * 512], Kg + (size_t)rr * HD + schunk * 8);
    async_copy16(&Vb[0][seg * 512], Vg + (size_t)rr * T + schunk * 8);
  }

  for (int kt = 0; kt <= qhi; ++kt) {
    __syncthreads();  // drains vmcnt -> tile kt ready; prev compute done
    if (kt < qhi) {
#pragma unroll
      for (int i = 0; i < 2; ++i) {
        const int seg = w * 2 + i;
        const int rr = seg * 8 + srow;
        async_copy16(&Kb[buf ^ 1][seg * 512],
                     Kg + (size_t)((kt + 1) * 64 + rr) * HD + schunk * 8);
        async_copy16(&Vb[buf ^ 1][seg * 512],
                     Vg + (size_t)rr * T + (kt + 1) * 64 + schunk * 8);
      }
    }
    f32x4 s[4];
    _Float16 ph[4][4];
    // ---- HI q-tile (always active) ----
    qkt_tile(qfh, &Kb[buf][0], s, lr, lk);
    if (kt == qhi) {  // causal: mask kv_local > q_local
#pragma unroll
      for (int ct = 0; ct < 4; ++ct)
#pragma unroll
        for (int r = 0; r < 4; ++r)
          if (ct * 16 + lk * 4 + r > w * 16 + lr) s[ct][r] = -INFINITY;
    }
    online_sm(s, mh, lh, acch, ph, l);
    pv_tile(ph, &Pb[0], &Vb[buf][0], acch, w, lr, lk);
    // ---- LO q-tile (active for kt <= qlo; block-uniform branch) ----
    if (kt <= qlo) {
      qkt_tile(qfl, &Kb[buf][0], s, lr, lk);
      if (kt == qlo) {
#pragma unroll
        for (int ct = 0; ct < 4; ++ct)
#pragma unroll
          for (int r = 0; r < 4; ++r)
            if (ct * 16 + lk * 4 + r > w * 16 + lr) s[ct][r] = -INFINITY;
      }
      online_sm(s, ml, ll, accl, ph, l);
      pv_tile(ph, &Pb[0], &Vb[buf][0], accl, w, lr, lk);
    }
    buf ^= 1;
  }
  // ---- epilogue: normalize (gather per-row l), write fp16 [b][t][h*64+d] ----
  const int bb = bh >> 4, h = bh & 15;
#pragma unroll
  for (int r = 0; r < 4; ++r) {
    const float lh_r = __shfl(lh, (l & 48) | (lk * 4 + r), 64);
    const float invh = 1.0f / lh_r;
    const int th = qhi * 64 + w * 16 + lk * 4 + r;
#pragma unroll
    for (int dt = 0; dt < 4; ++dt)
      O[((size_t)bb * T + th) * C + h * 64 + dt * 16 + lr] = (_Float16)(acch[dt][r] * invh);
    const float ll_r = __shfl(ll, (l & 48) | (lk * 4 + r), 64);
    const float invl = 1.0f / ll_r;
    const int tl = qlo * 64 + w * 16 + lk * 4 + r;
#pragma unroll
    for (int dt = 0; dt < 4; ++dt)
      O[((size_t)bb * T + tl) * C + h * 64 + dt * 16 + lr] = (_Float16)(accl[dt][r] * invl);
  }
}

// ---------------------------------------------------------------------------
extern "C" void kernel_launch(void* const* d_in, const int* in_sizes, int n_in,
                              void* d_out, int out_size, void* d_ws, size_t ws_size,
                              hipStream_t stream) {
  (void)in_sizes; (void)n_in; (void)out_size; (void)ws_size;
  const float* x   = (const float*)d_in[0];
  const float* Wq  = (const float*)d_in[1];
  const float* Wk  = (const float*)d_in[2];
  const float* Wv  = (const float*)d_in[3];
  const float* Wo  = (const float*)d_in[4];
  const float* bo  = (const float*)d_in[5];
  const float* g1  = (const float*)d_in[6];
  const float* be1 = (const float*)d_in[7];
  const float* g2  = (const float*)d_in[8];
  const float* be2 = (const float*)d_in[9];
  const float* W1  = (const float*)d_in[10];
  const float* b1  = (const float*)d_in[11];
  const float* W2  = (const float*)d_in[12];
  const float* b2  = (const float*)d_in[13];
  float* out = (float*)d_out;

  char* base = (char*)d_ws;
  _Float16* norm_h = (_Float16*)base;                    // 0..16 MB
  _Float16* WcatT  = (_Float16*)(base + (16ull << 20));  // 16..22 [3072][1024]
  _Float16* WoT    = (_Float16*)(base + (22ull << 20));  // 22..24 [1024][1024]
  _Float16* W1T    = (_Float16*)(base + (24ull << 20));  // 24..32 [4096][1024]
  _Float16* W2T    = (_Float16*)(base + (32ull << 20));  // 32..40 [1024][4096]
  _Float16* Qhb    = (_Float16*)(base + (40ull << 20));  // 40..56 [bh][t][d]
  _Float16* Khb    = (_Float16*)(base + (56ull << 20));  // 56..72 [bh][t][d]
  _Float16* Vthb   = (_Float16*)(base + (72ull << 20));  // 72..88 [bh][d][t]
  _Float16* attnCh = (_Float16*)(base + (88ull << 20));  // 88..104 [M][C]
  float* res       = (float*)(base + (104ull << 20));    // 104..136 fp32
  _Float16* hbuf   = (_Float16*)(base + (40ull << 20));  // 40..104, aliases QKV/attnC (dead)
  // total 136 MB

  tconv_qkv<<<dim3(16, 16, 3), 256, 0, stream>>>(Wq, Wk, Wv, WcatT);
  tconv<<<dim3(16, 16), 256, 0, stream>>>(Wo, WoT, C, C);
  tconv<<<dim3(64, 16), 256, 0, stream>>>(W1, W1T, C, F);
  tconv<<<dim3(16, 64), 256, 0, stream>>>(W2, W2T, F, C);

  ln_kernel<<<M, 256, 0, stream>>>(x, g1, be1, norm_h);
  mgemm<0><<<dim3(3072 / 128, M / 128), 256, 0, stream>>>(
      norm_h, WcatT, nullptr, nullptr, nullptr, Qhb, Khb, Vthb, 3072, C);
  attn_mfma<<<dim3(NT / 2, Bsz * H), 256, 0, stream>>>(Qhb, Khb, Vthb, attnCh);
  mgemm<1><<<dim3(C / 128, M / 128), 256, 0, stream>>>(
      attnCh, WoT, bo, x, res, nullptr, nullptr, nullptr, C, C);
  ln_kernel<<<M, 256, 0, stream>>>(res, g2, be2, norm_h);
  mgemm<2><<<dim3(F / 128, M / 128), 256, 0, stream>>>(
      norm_h, W1T, b1, nullptr, nullptr, hbuf, nullptr, nullptr, F, C);
  mgemm<3><<<dim3(C / 128, M / 128), 256, 0, stream>>>(
      hbuf, W2T, b2, res, out, nullptr, nullptr, nullptr, C, F);
}

// Round 12
// 563.694 us; speedup vs baseline: 6.7368x; 1.0928x over previous
//
#include <hip/hip_runtime.h>
#include <math.h>

// Problem constants (DecoderLayer, fp32 in/out)
constexpr int Bsz = 4, T = 2048, C = 1024, H = 16, HD = 64, F = 4096;
constexpr int M = Bsz * T;  // 8192 rows
constexpr int NT = T / 64;  // 32 KV tiles

typedef _Float16 f16x8 __attribute__((ext_vector_type(8)));
typedef float f32x4 __attribute__((ext_vector_type(4)));
typedef unsigned int u32;

__device__ __forceinline__ void async_copy16(void* lds, const void* g) {
  __builtin_amdgcn_global_load_lds((const __attribute__((address_space(1))) u32*)g,
                                   (__attribute__((address_space(3))) u32*)lds, 16, 0, 0);
}

union H4 { _Float16 h[4]; uint2 u; };

// ---------------------------------------------------------------------------
// LayerNorm: one block per row (1024 floats), 256 threads * float4, fp16 out
// ---------------------------------------------------------------------------
__global__ __launch_bounds__(256) void ln_kernel(const float* __restrict__ x,
                                                 const float* __restrict__ g,
                                                 const float* __restrict__ b,
                                                 _Float16* __restrict__ outh) {
  const int row = blockIdx.x;
  const int tid = threadIdx.x;
  const float4 v = ((const float4*)(x + (size_t)row * C))[tid];
  float s = v.x + v.y + v.z + v.w;
  float ss = v.x * v.x + v.y * v.y + v.z * v.z + v.w * v.w;
#pragma unroll
  for (int off = 32; off > 0; off >>= 1) {
    s += __shfl_xor(s, off, 64);
    ss += __shfl_xor(ss, off, 64);
  }
  __shared__ float red[2][4];
  const int wv = tid >> 6;
  if ((tid & 63) == 0) { red[0][wv] = s; red[1][wv] = ss; }
  __syncthreads();
  s = red[0][0] + red[0][1] + red[0][2] + red[0][3];
  ss = red[1][0] + red[1][1] + red[1][2] + red[1][3];
  const float mu = s * (1.0f / C);
  const float var = ss * (1.0f / C) - mu * mu;
  const float rstd = rsqrtf(var + 1e-5f);
  const float4 gv = ((const float4*)g)[tid];
  const float4 bv = ((const float4*)b)[tid];
  H4 pk;
  pk.h[0] = (_Float16)((v.x - mu) * rstd * gv.x + bv.x);
  pk.h[1] = (_Float16)((v.y - mu) * rstd * gv.y + bv.y);
  pk.h[2] = (_Float16)((v.z - mu) * rstd * gv.z + bv.z);
  pk.h[3] = (_Float16)((v.w - mu) * rstd * gv.w + bv.w);
  ((uint2*)(outh + (size_t)row * C))[tid] = pk.u;
}

// ---------------------------------------------------------------------------
// Generic transpose+convert: W[K][N] fp32 -> WT[N][K] fp16. grid (N/64, K/64)
// ---------------------------------------------------------------------------
__global__ __launch_bounds__(256) void tconv(const float* __restrict__ W,
                                             _Float16* __restrict__ WT,
                                             int K, int N) {
  __shared__ float tile[64][65];
  const int tid = threadIdx.x;
  const int n0 = blockIdx.x * 64, k0 = blockIdx.y * 64;
#pragma unroll
  for (int i = 0; i < 4; ++i) {
    const int idx = i * 1024 + tid * 4;
    const int r = idx >> 6, c = idx & 63;
    const float4 v = *(const float4*)&W[(size_t)(k0 + r) * N + n0 + c];
    tile[r][c] = v.x; tile[r][c + 1] = v.y; tile[r][c + 2] = v.z; tile[r][c + 3] = v.w;
  }
  __syncthreads();
#pragma unroll
  for (int i = 0; i < 4; ++i) {
    const int idx = i * 1024 + tid * 4;
    const int r = idx >> 6, c = idx & 63;
    H4 pk;
#pragma unroll
    for (int j = 0; j < 4; ++j) pk.h[j] = (_Float16)tile[c + j][r];
    *(uint2*)&WT[(size_t)(n0 + r) * K + k0 + c] = pk.u;
  }
}

// ---------------------------------------------------------------------------
// QKV weights: Wq/Wk/Wv [16][1024][64] fp32 -> WcatT [3072][1024] fp16
// ---------------------------------------------------------------------------
__global__ __launch_bounds__(256) void tconv_qkv(const float* __restrict__ Wq,
                                                 const float* __restrict__ Wk,
                                                 const float* __restrict__ Wv,
                                                 _Float16* __restrict__ WcatT) {
  __shared__ float tile[64][65];
  const int tid = threadIdx.x;
  const int c0 = blockIdx.x * 64;
  const int h = blockIdx.y, wsel = blockIdx.z;
  const float* W = (wsel == 0 ? Wq : (wsel == 1 ? Wk : Wv)) + (size_t)h * C * HD;
  const int base_row = wsel * 1024 + h * 64;
#pragma unroll
  for (int i = 0; i < 4; ++i) {
    const int idx = i * 1024 + tid * 4;
    const int r = idx >> 6, c = idx & 63;
    const float4 v = *(const float4*)&W[(size_t)(c0 + r) * HD + c];
    tile[r][c] = v.x; tile[r][c + 1] = v.y; tile[r][c + 2] = v.z; tile[r][c + 3] = v.w;
  }
  __syncthreads();
#pragma unroll
  for (int i = 0; i < 4; ++i) {
    const int idx = i * 1024 + tid * 4;
    const int r = idx >> 6, c = idx & 63;
    H4 pk;
#pragma unroll
    for (int j = 0; j < 4; ++j) pk.h[j] = (_Float16)tile[c + j][r];
    *(uint2*)&WcatT[(size_t)(base_row + r) * C + c0 + c] = pk.u;
  }
}

// ---------------------------------------------------------------------------
// Deep-pipelined MFMA fp16 GEMM (T2+T3+T4+T5): C = A[M,K] @ B^T (B is [N][K]).
// 256x128 tile, BK=64, 512 threads = 8 waves (4M x 2N), per-wave 64x64.
// Triple-buffered swizzled LDS (144 KB), prefetch depth 2, counted
// s_waitcnt vmcnt(6) + raw s_barrier once per K-tile (drain only at end).
// LDS swizzle: chunk ^= (row & 7), applied via pre-swizzled global source
// feeding linear global_load_lds (rule 21) and the same XOR on reads.
// MODE 0: QKV -> Qh fp16 (scaled log2e/8) [bh][t][d], Kh [bh][t][d],
//               Vth transposed [bh][d][t]
// MODE 1: WO  -> +bias +resid, fp32 out
// MODE 2: FFN1-> +bias, GELU, fp16 out
// MODE 3: FFN2-> +bias +resid, fp32 out
// ---------------------------------------------------------------------------
template <int MODE>
__global__ __launch_bounds__(512) void mgemm8(const _Float16* __restrict__ Ah,
                                              const _Float16* __restrict__ Bh,
                                              const float* __restrict__ bias,
                                              const float* __restrict__ resid,
                                              float* __restrict__ Of,
                                              _Float16* __restrict__ Oh,
                                              _Float16* __restrict__ Oh2,
                                              _Float16* __restrict__ Oh3,
                                              int Ndim, int Kdim) {
  __shared__ __attribute__((aligned(16))) _Float16 Alds[3][256 * 64];
  __shared__ __attribute__((aligned(16))) _Float16 Blds[3][128 * 64];
  const int tid = threadIdx.x;
  const int wv = tid >> 6, l = tid & 63;
  const int wm = wv & 3, wn = wv >> 2;  // 4 M-waves x 2 N-waves
  const int lr = l & 15, lk = l >> 4;
  const int srow = l >> 3;             // row within 8-row stage segment
  const int schunk = (l & 7) ^ srow;   // pre-swizzled source chunk

  // XCD-aware swizzle (T1): all grids have nwg % 8 == 0
  int bx = blockIdx.x, by = blockIdx.y;
  {
    const int gx = gridDim.x;
    const int nwg = gx * gridDim.y;
    int wg = by * gx + bx;
    wg = (wg & 7) * (nwg >> 3) + (wg >> 3);
    bx = wg % gx;
    by = wg / gx;
  }
  const int m0 = by * 256, n0 = bx * 128;
  const _Float16* Abase = Ah + (size_t)m0 * Kdim;
  const _Float16* Bbase = Bh + (size_t)n0 * Kdim;
  const int ksteps = Kdim >> 6;

  f32x4 acc[4][4] = {};

  // stage-issue: grp 0 = A segs 0..2 (3 loads), grp 1 = A seg 3 + B segs 0..1
  auto stage_grp = [&](int t, int grp) {
    const size_t kofs = (size_t)t << 6;
    _Float16* Al = &Alds[t % 3][0];
    _Float16* Bl = &Blds[t % 3][0];
    if (grp == 0) {
#pragma unroll
      for (int i = 0; i < 3; ++i) {
        const int seg = wv * 4 + i;  // 8 rows each, rows 0..255
        async_copy16(Al + seg * 512,
                     Abase + (size_t)(seg * 8 + srow) * Kdim + kofs + schunk * 8);
      }
    } else {
      {
        const int seg = wv * 4 + 3;
        async_copy16(Al + seg * 512,
                     Abase + (size_t)(seg * 8 + srow) * Kdim + kofs + schunk * 8);
      }
#pragma unroll
      for (int i = 0; i < 2; ++i) {
        const int seg = wv * 2 + i;  // rows 0..127
        async_copy16(Bl + seg * 512,
                     Bbase + (size_t)(seg * 8 + srow) * Kdim + kofs + schunk * 8);
      }
    }
  };

  // prologue: prefetch tiles 0 and 1 (12 loads in flight per wave)
  stage_grp(0, 0); stage_grp(0, 1);
  stage_grp(1, 0); stage_grp(1, 1);

  for (int t = 0; t < ksteps; ++t) {
    // tile t's 6 loads are the oldest; newest 6 (tile t+1) may stay in flight
    if (t + 1 < ksteps)
      asm volatile("s_waitcnt vmcnt(6)" ::: "memory");
    else
      asm volatile("s_waitcnt vmcnt(0)" ::: "memory");
    __builtin_amdgcn_s_barrier();
    asm volatile("" ::: "memory");
    const _Float16* Al = &Alds[t % 3][0];
    const _Float16* Bl = &Blds[t % 3][0];

    f16x8 af[4], bf[4];
    // kk = 0 fragment reads (swizzled: chunk = lk ^ (row&7))
#pragma unroll
    for (int fm = 0; fm < 4; ++fm) {
      const int row = wm * 64 + fm * 16 + lr;
      af[fm] = *(const f16x8*)&Al[row * 64 + (lk ^ (row & 7)) * 8];
    }
#pragma unroll
    for (int fn = 0; fn < 4; ++fn) {
      const int row = wn * 64 + fn * 16 + lr;
      bf[fn] = *(const f16x8*)&Bl[row * 64 + (lk ^ (row & 7)) * 8];
    }
    if (t + 2 < ksteps) stage_grp(t + 2, 0);
    __builtin_amdgcn_s_setprio(1);
#pragma unroll
    for (int fm = 0; fm < 4; ++fm)
#pragma unroll
      for (int fn = 0; fn < 4; ++fn)
        acc[fm][fn] = __builtin_amdgcn_mfma_f32_16x16x32_f16(af[fm], bf[fn], acc[fm][fn], 0, 0, 0);
    __builtin_amdgcn_s_setprio(0);
    // kk = 1
#pragma unroll
    for (int fm = 0; fm < 4; ++fm) {
      const int row = wm * 64 + fm * 16 + lr;
      af[fm] = *(const f16x8*)&Al[row * 64 + ((4 + lk) ^ (row & 7)) * 8];
    }
#pragma unroll
    for (int fn = 0; fn < 4; ++fn) {
      const int row = wn * 64 + fn * 16 + lr;
      bf[fn] = *(const f16x8*)&Bl[row * 64 + ((4 + lk) ^ (row & 7)) * 8];
    }
    if (t + 2 < ksteps) stage_grp(t + 2, 1);
    __builtin_amdgcn_s_setprio(1);
#pragma unroll
    for (int fm = 0; fm < 4; ++fm)
#pragma unroll
      for (int fn = 0; fn < 4; ++fn)
        acc[fm][fn] = __builtin_amdgcn_mfma_f32_16x16x32_f16(af[fm], bf[fn], acc[fm][fn], 0, 0, 0);
    __builtin_amdgcn_s_setprio(0);
  }

  // Epilogue. D layout: col = l&15, row = (l>>4)*4 + r
#pragma unroll
  for (int fm = 0; fm < 4; ++fm) {
#pragma unroll
    for (int fn = 0; fn < 4; ++fn) {
      const int row0 = m0 + wm * 64 + fm * 16 + lk * 4;
      const int col = n0 + wn * 64 + fn * 16 + lr;
      const f32x4 v = acc[fm][fn];
      if (MODE == 0) {
        const int wsel = col >> 10, h = (col >> 6) & 15, d = col & 63;
#pragma unroll
        for (int r = 0; r < 4; ++r) {
          const int m = row0 + r;
          const int bb = m >> 11, t = m & (T - 1);
          if (wsel == 0)  // fold 1/sqrt(64) * log2(e): attention works in exp2 domain
            Oh[(((size_t)bb * H + h) * T + t) * HD + d] = (_Float16)(v[r] * 0.18033688011112042f);
          else if (wsel == 1)
            Oh2[(((size_t)bb * H + h) * T + t) * HD + d] = (_Float16)v[r];
          else
            Oh3[(((size_t)bb * H + h) * HD + d) * T + t] = (_Float16)v[r];
        }
      } else if (MODE == 1 || MODE == 3) {
        const float bc = bias[col];
#pragma unroll
        for (int r = 0; r < 4; ++r)
          Of[(size_t)(row0 + r) * Ndim + col] =
              v[r] + bc + resid[(size_t)(row0 + r) * Ndim + col];
      } else {  // MODE 2: GELU -> fp16
        const float bc = bias[col];
#pragma unroll
        for (int r = 0; r < 4; ++r) {
          float tt = v[r] + bc;
          tt = 0.5f * tt * (1.0f + erff(tt * 0.70710678118654752f));
          Oh[(size_t)(row0 + r) * Ndim + col] = (_Float16)tt;
        }
      }
    }
  }
}

// ---------------------------------------------------------------------------
// Attention helpers. SWAPPED QK^T: compute mfma(K,Q) so D[kv][q] with
// q = col = l&15 -> each lane holds 16 kv-scores for ONE q in registers.
// Row-reduce = in-register tree + 2 shfl_xor (x16, x32). Scores pre-scaled
// by log2e/8 -> exp2 softmax. T13 defer-max (THR=8, P bounded by 2^8).
// ---------------------------------------------------------------------------
__device__ __forceinline__ void qkt_tile(const f16x8 (&qf)[2],
                                         const _Float16* __restrict__ Kbuf,
                                         f32x4 (&s)[4], int lr, int lk) {
  __builtin_amdgcn_s_setprio(1);
#pragma unroll
  for (int ct = 0; ct < 4; ++ct) {
    s[ct] = f32x4{0.f, 0.f, 0.f, 0.f};
#pragma unroll
    for (int kk = 0; kk < 2; ++kk) {
      const int row = ct * 16 + lr;
      const int ch = (kk * 4 + lk) ^ (row & 7);
      const f16x8 kf = *(const f16x8*)&Kbuf[row * 64 + ch * 8];
      s[ct] = __builtin_amdgcn_mfma_f32_16x16x32_f16(kf, qf[kk], s[ct], 0, 0, 0);
    }
  }
  __builtin_amdgcn_s_setprio(0);
}

// s[ct][r] = S[kv_local = ct*16 + lk*4 + r][q_local = lr], per-lane stats for q=lr
__device__ __forceinline__ void online_sm(const f32x4 (&s)[4], float& m_i, float& l_i,
                                          f32x4 (&acc)[4], _Float16 (&ph)[4][4], int l) {
  float mx = fmaxf(fmaxf(s[0][0], s[0][1]), fmaxf(s[0][2], s[0][3]));
#pragma unroll
  for (int ct = 1; ct < 4; ++ct)
    mx = fmaxf(mx, fmaxf(fmaxf(s[ct][0], s[ct][1]), fmaxf(s[ct][2], s[ct][3])));
  mx = fmaxf(mx, __shfl_xor(mx, 16, 64));
  mx = fmaxf(mx, __shfl_xor(mx, 32, 64));
  float mn = fmaxf(m_i, mx);
  if (__all(mx - m_i <= 8.0f)) {
    mn = m_i;  // defer: keep old max; P values bounded by 2^8 (fp16-safe)
  } else {
    const float alpha = exp2f(m_i - mn);
    m_i = mn;
    l_i *= alpha;
#pragma unroll
    for (int r = 0; r < 4; ++r) {
      const float a_r = __shfl(alpha, (l & 48) | (((l >> 4) & 3) * 4 + r), 64);
#pragma unroll
      for (int dt = 0; dt < 4; ++dt) acc[dt][r] *= a_r;
    }
  }
  float rs = 0.f;
#pragma unroll
  for (int ct = 0; ct < 4; ++ct)
#pragma unroll
    for (int r = 0; r < 4; ++r) {
      const float p = exp2f(s[ct][r] - mn);
      rs += p;
      ph[ct][r] = (_Float16)p;
    }
  rs += __shfl_xor(rs, 16, 64);
  rs += __shfl_xor(rs, 32, 64);
  l_i += rs;
}

__device__ __forceinline__ void pv_tile(const _Float16 (&ph)[4][4], _Float16* Pb,
                                        const _Float16* __restrict__ Vbuf,
                                        f32x4 (&acc)[4], int w, int lr, int lk) {
  const int qw = w * 16 + lr;
#pragma unroll
  for (int ct = 0; ct < 4; ++ct)
#pragma unroll
    for (int r = 0; r < 4; ++r) {
      const int kv = ct * 16 + lk * 4 + r;
      Pb[qw * 64 + (kv ^ ((qw & 7) * 8))] = ph[ct][r];
    }
  __builtin_amdgcn_s_setprio(1);
#pragma unroll
  for (int kk = 0; kk < 2; ++kk) {
    const int pch = (kk * 4 + lk) ^ (qw & 7);
    const f16x8 pa = *(const f16x8*)&Pb[qw * 64 + pch * 8];
#pragma unroll
    for (int dt = 0; dt < 4; ++dt) {
      const int drow = dt * 16 + lr;
      const int vch = (kk * 4 + lk) ^ (drow & 7);
      const f16x8 vf = *(const f16x8*)&Vbuf[drow * 64 + vch * 8];
      acc[dt] = __builtin_amdgcn_mfma_f32_16x16x32_f16(pa, vf, acc[dt], 0, 0, 0);
    }
  }
  __builtin_amdgcn_s_setprio(0);
}

// ---------------------------------------------------------------------------
// MFMA flash attention (causal), PAIRED q-tiles for load balance.
// grid (NT/2=16, B*H), 256 threads = 4 waves. Block b owns q-tiles
// {b, NT-1-b} -> every block computes exactly NT+1 tile-products.
// K/V staged once per kt serve both q-tiles. LDS 40KB -> 4 blocks/CU.
// ---------------------------------------------------------------------------
__global__ __launch_bounds__(256) void attn_mfma(const _Float16* __restrict__ Qh,
                                                 const _Float16* __restrict__ Kh,
                                                 const _Float16* __restrict__ Vth,
                                                 _Float16* __restrict__ O) {
  __shared__ _Float16 Kb[2][64 * 64];
  __shared__ _Float16 Vb[2][64 * 64];
  __shared__ _Float16 Pb[64 * 64];
  const int tid = threadIdx.x;
  const int w = tid >> 6, l = tid & 63;
  const int lr = l & 15, lk = l >> 4;
  const int qlo = blockIdx.x, qhi = (NT - 1) - blockIdx.x;
  const int bh = blockIdx.y;
  const _Float16* Qg = Qh + (size_t)bh * T * HD;
  const _Float16* Kg = Kh + (size_t)bh * T * HD;
  const _Float16* Vg = Vth + (size_t)bh * HD * T;

  f16x8 qfl[2], qfh[2];
#pragma unroll
  for (int kk = 0; kk < 2; ++kk) {
    qfl[kk] = *(const f16x8*)&Qg[(size_t)(qlo * 64 + w * 16 + lr) * HD + kk * 32 + lk * 8];
    qfh[kk] = *(const f16x8*)&Qg[(size_t)(qhi * 64 + w * 16 + lr) * HD + kk * 32 + lk * 8];
  }

  f32x4 accl[4] = {}, acch[4] = {};
  float ml = -INFINITY, ll = 0.f, mh = -INFINITY, lh = 0.f;

  const int srow = l >> 3;
  const int schunk = (l & 7) ^ srow;

  int buf = 0;
#pragma unroll
  for (int i = 0; i < 2; ++i) {
    const int seg = w * 2 + i;
    const int rr = seg * 8 + srow;
    async_copy16(&Kb[0][seg * 512], Kg + (size_t)rr * HD + schunk * 8);
    async_copy16(&Vb[0][seg * 512], Vg + (size_t)rr * T + schunk * 8);
  }

  for (int kt = 0; kt <= qhi; ++kt) {
    __syncthreads();
    if (kt < qhi) {
#pragma unroll
      for (int i = 0; i < 2; ++i) {
        const int seg = w * 2 + i;
        const int rr = seg * 8 + srow;
        async_copy16(&Kb[buf ^ 1][seg * 512],
                     Kg + (size_t)((kt + 1) * 64 + rr) * HD + schunk * 8);
        async_copy16(&Vb[buf ^ 1][seg * 512],
                     Vg + (size_t)rr * T + (kt + 1) * 64 + schunk * 8);
      }
    }
    f32x4 s[4];
    _Float16 ph[4][4];
    // ---- HI q-tile (always active) ----
    qkt_tile(qfh, &Kb[buf][0], s, lr, lk);
    if (kt == qhi) {
#pragma unroll
      for (int ct = 0; ct < 4; ++ct)
#pragma unroll
        for (int r = 0; r < 4; ++r)
          if (ct * 16 + lk * 4 + r > w * 16 + lr) s[ct][r] = -INFINITY;
    }
    online_sm(s, mh, lh, acch, ph, l);
    pv_tile(ph, &Pb[0], &Vb[buf][0], acch, w, lr, lk);
    // ---- LO q-tile (active for kt <= qlo; block-uniform branch) ----
    if (kt <= qlo) {
      qkt_tile(qfl, &Kb[buf][0], s, lr, lk);
      if (kt == qlo) {
#pragma unroll
        for (int ct = 0; ct < 4; ++ct)
#pragma unroll
          for (int r = 0; r < 4; ++r)
            if (ct * 16 + lk * 4 + r > w * 16 + lr) s[ct][r] = -INFINITY;
      }
      online_sm(s, ml, ll, accl, ph, l);
      pv_tile(ph, &Pb[0], &Vb[buf][0], accl, w, lr, lk);
    }
    buf ^= 1;
  }
  // ---- epilogue: normalize (gather per-row l), write fp16 [b][t][h*64+d] ----
  const int bb = bh >> 4, h = bh & 15;
#pragma unroll
  for (int r = 0; r < 4; ++r) {
    const float lh_r = __shfl(lh, (l & 48) | (lk * 4 + r), 64);
    const float invh = 1.0f / lh_r;
    const int th = qhi * 64 + w * 16 + lk * 4 + r;
#pragma unroll
    for (int dt = 0; dt < 4; ++dt)
      O[((size_t)bb * T + th) * C + h * 64 + dt * 16 + lr] = (_Float16)(acch[dt][r] * invh);
    const float ll_r = __shfl(ll, (l & 48) | (lk * 4 + r), 64);
    const float invl = 1.0f / ll_r;
    const int tl = qlo * 64 + w * 16 + lk * 4 + r;
#pragma unroll
    for (int dt = 0; dt < 4; ++dt)
      O[((size_t)bb * T + tl) * C + h * 64 + dt * 16 + lr] = (_Float16)(accl[dt][r] * invl);
  }
}

// ---------------------------------------------------------------------------
extern "C" void kernel_launch(void* const* d_in, const int* in_sizes, int n_in,
                              void* d_out, int out_size, void* d_ws, size_t ws_size,
                              hipStream_t stream) {
  (void)in_sizes; (void)n_in; (void)out_size; (void)ws_size;
  const float* x   = (const float*)d_in[0];
  const float* Wq  = (const float*)d_in[1];
  const float* Wk  = (const float*)d_in[2];
  const float* Wv  = (const float*)d_in[3];
  const float* Wo  = (const float*)d_in[4];
  const float* bo  = (const float*)d_in[5];
  const float* g1  = (const float*)d_in[6];
  const float* be1 = (const float*)d_in[7];
  const float* g2  = (const float*)d_in[8];
  const float* be2 = (const float*)d_in[9];
  const float* W1  = (const float*)d_in[10];
  const float* b1  = (const float*)d_in[11];
  const float* W2  = (const float*)d_in[12];
  const float* b2  = (const float*)d_in[13];
  float* out = (float*)d_out;

  char* base = (char*)d_ws;
  _Float16* norm_h = (_Float16*)base;                    // 0..16 MB
  _Float16* WcatT  = (_Float16*)(base + (16ull << 20));  // 16..22 [3072][1024]
  _Float16* WoT    = (_Float16*)(base + (22ull << 20));  // 22..24 [1024][1024]
  _Float16* W1T    = (_Float16*)(base + (24ull << 20));  // 24..32 [4096][1024]
  _Float16* W2T    = (_Float16*)(base + (32ull << 20));  // 32..40 [1024][4096]
  _Float16* Qhb    = (_Float16*)(base + (40ull << 20));  // 40..56 [bh][t][d]
  _Float16* Khb    = (_Float16*)(base + (56ull << 20));  // 56..72 [bh][t][d]
  _Float16* Vthb   = (_Float16*)(base + (72ull << 20));  // 72..88 [bh][d][t]
  _Float16* attnCh = (_Float16*)(base + (88ull << 20));  // 88..104 [M][C]
  float* res       = (float*)(base + (104ull << 20));    // 104..136 fp32
  _Float16* hbuf   = (_Float16*)(base + (40ull << 20));  // 40..104, aliases QKV/attnC (dead)
  // total 136 MB

  tconv_qkv<<<dim3(16, 16, 3), 256, 0, stream>>>(Wq, Wk, Wv, WcatT);
  tconv<<<dim3(16, 16), 256, 0, stream>>>(Wo, WoT, C, C);
  tconv<<<dim3(64, 16), 256, 0, stream>>>(W1, W1T, C, F);
  tconv<<<dim3(16, 64), 256, 0, stream>>>(W2, W2T, F, C);

  ln_kernel<<<M, 256, 0, stream>>>(x, g1, be1, norm_h);
  mgemm8<0><<<dim3(3072 / 128, M / 256), 512, 0, stream>>>(
      norm_h, WcatT, nullptr, nullptr, nullptr, Qhb, Khb, Vthb, 3072, C);
  attn_mfma<<<dim3(NT / 2, Bsz * H), 256, 0, stream>>>(Qhb, Khb, Vthb, attnCh);
  mgemm8<1><<<dim3(C / 128, M / 256), 512, 0, stream>>>(
      attnCh, WoT, bo, x, res, nullptr, nullptr, nullptr, C, C);
  ln_kernel<<<M, 256, 0, stream>>>(res, g2, be2, norm_h);
  mgemm8<2><<<dim3(F / 128, M / 256), 512, 0, stream>>>(
      norm_h, W1T, b1, nullptr, nullptr, hbuf, nullptr, nullptr, F, C);
  mgemm8<3><<<dim3(C / 128, M / 256), 512, 0, stream>>>(
      hbuf, W2T, b2, res, out, nullptr, nullptr, nullptr, C, F);
}